// Round 2
// baseline (1421.076 us; speedup 1.0000x reference)
//
#include <hip/hip_runtime.h>
#include <hip/hip_bf16.h>

typedef __hip_bfloat16 bf16;

#define N_NODES 50000
#define E_EDGES 800000
#define EA (E_EDGES + N_NODES)   // 850000 edges incl self-loops
#define HC 128                   // heads*dim
#define HEADS 4
#define DIM 32
#define DIM2 16
#define NCLS 6
#define SLOPE 0.2f

__device__ __forceinline__ float b2f(bf16 v) { return __bfloat162float(v); }

// ---------------- dtype detector ----------------
// flags[0]=1 -> float inputs (and output) are fp32; 0 -> bf16
// flags[1]=1 -> edge_index is int64; 0 -> int32
__global__ __launch_bounds__(256) void k_detect(const void* wptr, const void* eptr,
                                                int* __restrict__ flags) {
    __shared__ int sb[256], sn[256];
    int tid = threadIdx.x;
    const unsigned short* w = (const unsigned short*)wptr;
    int badf = 0;
    for (int i = tid; i < 4096; i += 256) {
        unsigned v = w[i];
        unsigned ex = (v >> 7) & 0xFF;
        if (v != 0 && (ex < 90 || ex > 150)) badf++;
    }
    const int* ei = (const int*)eptr;
    int nz = 0;
    for (int i = tid; i < 2048; i += 256) {
        if (ei[2 * i + 1] != 0) nz++;
    }
    sb[tid] = badf; sn[tid] = nz;
    __syncthreads();
    for (int ofs = 128; ofs > 0; ofs >>= 1) {
        if (tid < ofs) { sb[tid] += sb[tid + ofs]; sn[tid] += sn[tid + ofs]; }
        __syncthreads();
    }
    if (tid == 0) {
        flags[0] = (sb[0] > 64) ? 1 : 0;   // many wild exponents -> fp32 data
        flags[1] = (sn[0] < 64) ? 1 : 0;   // odd words all zero -> int64 data
    }
}

// ---------------- input normalization to fp32 / int32 ----------------
__global__ void k_cvt(const void* __restrict__ src, float* __restrict__ dst, int n,
                      const int* __restrict__ flags) {
    int i = blockIdx.x * blockDim.x + threadIdx.x;
    if (i >= n) return;
    if (flags[0]) dst[i] = ((const float*)src)[i];
    else          dst[i] = b2f(((const bf16*)src)[i]);
}

__global__ void k_cvti(const void* __restrict__ src, int* __restrict__ dst, int n,
                       const int* __restrict__ flags) {
    int i = blockIdx.x * blockDim.x + threadIdx.x;
    if (i >= n) return;
    int v;
    if (flags[1]) v = (int)((const long long*)src)[i];
    else          v = ((const int*)src)[i];
    // clamp defensively to a valid node id
    if (v < 0) v = 0;
    if (v >= N_NODES) v = N_NODES - 1;
    dst[i] = v;
}

// ---------------- CSR build ----------------
__global__ void k_zero(int* __restrict__ off, int* __restrict__ fill) {
    int i = blockIdx.x * blockDim.x + threadIdx.x;
    if (i <= N_NODES) off[i] = 0;
    if (i < N_NODES) fill[i] = 0;
}

__global__ void k_hist(const int* __restrict__ eidx, int* __restrict__ off) {
    int e = blockIdx.x * blockDim.x + threadIdx.x;
    if (e >= EA) return;
    int dst = (e < E_EDGES) ? eidx[E_EDGES + e] : (e - E_EDGES);
    atomicAdd(&off[dst], 1);
}

// single-block in-place exclusive scan of off[0..N), writes off[N]
__global__ __launch_bounds__(1024) void k_scan(int* __restrict__ off) {
    __shared__ int sdata[1024];
    int tid = threadIdx.x;
    int running = 0;
    for (int base = 0; base < N_NODES; base += 1024) {
        int i = base + tid;
        int v = (i < N_NODES) ? off[i] : 0;
        sdata[tid] = v;
        __syncthreads();
        for (int ofs = 1; ofs < 1024; ofs <<= 1) {
            int t = (tid >= ofs) ? sdata[tid - ofs] : 0;
            __syncthreads();
            sdata[tid] += t;
            __syncthreads();
        }
        int incl = sdata[tid];
        if (i < N_NODES) off[i] = running + incl - v;   // exclusive
        int total = sdata[1023];
        running += total;
        __syncthreads();
    }
    if (tid == 0) off[N_NODES] = running;
}

__global__ void k_scatter(const int* __restrict__ eidx, const int* __restrict__ off,
                          int* __restrict__ fill, int* __restrict__ csrsrc) {
    int e = blockIdx.x * blockDim.x + threadIdx.x;
    if (e >= EA) return;
    int src, dst;
    if (e < E_EDGES) { src = eidx[e]; dst = eidx[E_EDGES + e]; }
    else             { src = dst = e - E_EDGES; }
    int pos = off[dst] + atomicAdd(&fill[dst], 1);
    if (pos >= 0 && pos < EA) csrsrc[pos] = src;
}

// ---------------- xl/xr = h @ Wl + bl, h @ Wr + br (all fp32) ----------------
#define GROWS 32
__global__ __launch_bounds__(128) void k_gemm2(
        const float* __restrict__ h,
        const float* __restrict__ Wl, const float* __restrict__ Wr,
        const float* __restrict__ bl, const float* __restrict__ br,
        float* __restrict__ xl, float* __restrict__ xr) {
    __shared__ __align__(16) float hs[GROWS * HC];
    int tid = threadIdx.x;
    long row0 = (long)blockIdx.x * GROWS;
    for (int idx = tid; idx < GROWS * HC; idx += 128) {
        long g = row0 * HC + idx;
        hs[idx] = (g < (long)N_NODES * HC) ? h[g] : 0.f;
    }
    __syncthreads();
    int col = tid;
    float accL[GROWS], accR[GROWS];
#pragma unroll
    for (int r = 0; r < GROWS; r++) { accL[r] = 0.f; accR[r] = 0.f; }
    const float4* hs4 = (const float4*)hs;
    for (int k = 0; k < HC; k += 4) {
        float wl0 = Wl[(k + 0) * HC + col];
        float wl1 = Wl[(k + 1) * HC + col];
        float wl2 = Wl[(k + 2) * HC + col];
        float wl3 = Wl[(k + 3) * HC + col];
        float wr0 = Wr[(k + 0) * HC + col];
        float wr1 = Wr[(k + 1) * HC + col];
        float wr2 = Wr[(k + 2) * HC + col];
        float wr3 = Wr[(k + 3) * HC + col];
#pragma unroll
        for (int r = 0; r < GROWS; r++) {
            float4 hv = hs4[(r * HC + k) >> 2];
            accL[r] += hv.x * wl0 + hv.y * wl1 + hv.z * wl2 + hv.w * wl3;
            accR[r] += hv.x * wr0 + hv.y * wr1 + hv.z * wr2 + hv.w * wr3;
        }
    }
    float blv = bl[col], brv = br[col];
    int nrows = (int)((N_NODES - row0) < GROWS ? (N_NODES - row0) : GROWS);
    for (int r = 0; r < nrows; r++) {
        xl[(row0 + r) * HC + col] = accL[r] + blv;
        xr[(row0 + r) * HC + col] = accR[r] + brv;
    }
}

// ---------------- GATv2 edge aggregation: one wave per node ----------------
// pass 1: max of attention logits; pass 2: recompute logits (bit-identical),
// online exp-sum and weighted aggregate. No global score round-trip.
__global__ __launch_bounds__(256) void k_attn(
        const float* __restrict__ xl, const float* __restrict__ xr,
        const int* __restrict__ off, const int* __restrict__ csrsrc,
        const float* __restrict__ att, const float* __restrict__ cb,
        float* __restrict__ hout) {
    int wave = threadIdx.x >> 6;
    int lane = threadIdx.x & 63;
    int node = blockIdx.x * 4 + wave;
    if (node >= N_NODES) return;
    int head = lane >> 4;
    int f0 = 2 * lane, f1 = 2 * lane + 1;
    float xr0 = xr[(long)node * HC + f0];
    float xr1 = xr[(long)node * HC + f1];
    float a0 = att[head * DIM + (f0 & 31)];
    float a1 = att[head * DIM + (f1 & 31)];
    int e0 = off[node], e1 = off[node + 1];
    if (e0 < 0) e0 = 0;
    if (e1 > EA) e1 = EA;
    float mmax = -1e30f;
    for (int k = e0; k < e1; k++) {
        int s = csrsrc[k];
        float xl0 = xl[(long)s * HC + f0];
        float xl1 = xl[(long)s * HC + f1];
        float m0 = xl0 + xr0, m1 = xl1 + xr1;
        float v0 = m0 > 0.f ? m0 : SLOPE * m0;
        float v1 = m1 > 0.f ? m1 : SLOPE * m1;
        float p = v0 * a0 + v1 * a1;
        p += __shfl_xor(p, 1);
        p += __shfl_xor(p, 2);
        p += __shfl_xor(p, 4);
        p += __shfl_xor(p, 8);   // 16-lane head group all hold the dot
        mmax = fmaxf(mmax, p);
    }
    float ssum = 0.f, acc0 = 0.f, acc1 = 0.f;
    for (int k = e0; k < e1; k++) {
        int s = csrsrc[k];
        float xl0 = xl[(long)s * HC + f0];
        float xl1 = xl[(long)s * HC + f1];
        float m0 = xl0 + xr0, m1 = xl1 + xr1;
        float v0 = m0 > 0.f ? m0 : SLOPE * m0;
        float v1 = m1 > 0.f ? m1 : SLOPE * m1;
        float p = v0 * a0 + v1 * a1;
        p += __shfl_xor(p, 1);
        p += __shfl_xor(p, 2);
        p += __shfl_xor(p, 4);
        p += __shfl_xor(p, 8);
        float ex = __expf(p - mmax);   // identical ops as pass 1 -> ex <= 1
        ssum += ex;
        acc0 += ex * xl0;
        acc1 += ex * xl1;
    }
    float inv = 1.f / (ssum + 1e-16f);
    float o0 = acc0 * inv + cb[f0];
    float o1 = acc1 * inv + cb[f1];
    hout[(long)node * HC + f0] = o0 > 0.f ? o0 : 0.f;
    hout[(long)node * HC + f1] = o1 > 0.f ? o1 : 0.f;
}

// ---------------- h2 = relu(h @ W1 + b1) : [N,128]@[128,32] ----------------
__global__ __launch_bounds__(256) void k_mlp1(
        const float* __restrict__ h, const float* __restrict__ W1,
        const float* __restrict__ b1, float* __restrict__ h2) {
    __shared__ float hs[8 * HC];
    __shared__ float w1s[HC * DIM];
    int tid = threadIdx.x;
    long row0 = (long)blockIdx.x * 8;
    for (int idx = tid; idx < HC * DIM; idx += 256) w1s[idx] = W1[idx];
    for (int idx = tid; idx < 8 * HC; idx += 256) {
        long g = row0 * HC + idx;
        hs[idx] = (g < (long)N_NODES * HC) ? h[g] : 0.f;
    }
    __syncthreads();
    int r = tid >> 5, c = tid & 31;
    float acc = b1[c];
    for (int k = 0; k < HC; k++) acc += hs[r * HC + k] * w1s[k * DIM + c];
    long row = row0 + r;
    if (row < N_NODES) h2[row * DIM + c] = acc > 0.f ? acc : 0.f;
}

// ---------------- h3 = relu(h2 @ W2 + b2) : [N,32]@[32,16] ----------------
__global__ __launch_bounds__(256) void k_mlp2(
        const float* __restrict__ h2, const float* __restrict__ W2,
        const float* __restrict__ b2, float* __restrict__ h3) {
    __shared__ float hs[16 * DIM];
    __shared__ float w2s[DIM * DIM2];
    int tid = threadIdx.x;
    long row0 = (long)blockIdx.x * 16;
    for (int idx = tid; idx < DIM * DIM2; idx += 256) w2s[idx] = W2[idx];
    for (int idx = tid; idx < 16 * DIM; idx += 256) {
        long g = row0 * DIM + idx;
        hs[idx] = (g < (long)N_NODES * DIM) ? h2[g] : 0.f;
    }
    __syncthreads();
    int r = tid >> 4, c = tid & 15;
    float acc = b2[c];
    for (int k = 0; k < DIM; k++) acc += hs[r * DIM + k] * w2s[k * DIM2 + c];
    long row = row0 + r;
    if (row < N_NODES) h3[row * DIM2 + c] = acc > 0.f ? acc : 0.f;
}

// ---------------- out0 = concat(h3[src],h3[dst]) @ W3 + b3 ----------------
__global__ __launch_bounds__(256) void k_out0(
        const float* __restrict__ h3, const int* __restrict__ eidx,
        const float* __restrict__ W3, const float* __restrict__ b3,
        void* __restrict__ dout, const int* __restrict__ flags) {
    __shared__ float w3s[2 * DIM2 * NCLS];
    __shared__ float bs[NCLS];
    int tid = threadIdx.x;
    if (tid < 2 * DIM2 * NCLS) w3s[tid] = W3[tid];
    if (tid < NCLS) bs[tid] = b3[tid];
    __syncthreads();
    int e = blockIdx.x * 256 + tid;
    if (e >= E_EDGES) return;
    int src = eidx[e], dst = eidx[E_EDGES + e];
    float v[2 * DIM2];
    const float4* ps = (const float4*)(h3 + (long)src * DIM2);
    const float4* pd = (const float4*)(h3 + (long)dst * DIM2);
#pragma unroll
    for (int q = 0; q < 4; q++) {
        float4 t = ps[q];
        v[q * 4 + 0] = t.x; v[q * 4 + 1] = t.y; v[q * 4 + 2] = t.z; v[q * 4 + 3] = t.w;
    }
#pragma unroll
    for (int q = 0; q < 4; q++) {
        float4 t = pd[q];
        v[16 + q * 4 + 0] = t.x; v[16 + q * 4 + 1] = t.y; v[16 + q * 4 + 2] = t.z; v[16 + q * 4 + 3] = t.w;
    }
    int f32out = flags[0];
#pragma unroll
    for (int j = 0; j < NCLS; j++) {
        float acc = bs[j];
#pragma unroll
        for (int k = 0; k < 2 * DIM2; k++) acc += v[k] * w3s[k * NCLS + j];
        long idx = (long)e * NCLS + j;
        if (f32out) ((float*)dout)[idx] = acc;
        else        ((bf16*)dout)[idx] = __float2bfloat16(acc);
    }
}

// ---------------- e_out gather, coalesced writes ----------------
__global__ void k_eout(const float* __restrict__ h3, const int* __restrict__ eidx,
                       void* __restrict__ dout, const int* __restrict__ flags) {
    long i = (long)blockIdx.x * blockDim.x + threadIdx.x;
    if (i >= (long)E_EDGES * 2 * DIM2) return;
    int e = (int)(i >> 5), k = (int)(i & 31);
    int node = (k < DIM2) ? eidx[e] : eidx[E_EDGES + e];
    float val = h3[(long)node * DIM2 + (k & 15)];
    long idx = (long)E_EDGES * NCLS + i;   // eout region follows out0 region
    if (flags[0]) ((float*)dout)[idx] = val;
    else          ((bf16*)dout)[idx] = __float2bfloat16(val);
}

extern "C" void kernel_launch(void* const* d_in, const int* in_sizes, int n_in,
                              void* d_out, int out_size, void* d_ws, size_t ws_size,
                              hipStream_t stream) {
    // ---- workspace layout (4-byte word offsets) ----
    float* wsf   = (float*)d_ws;
    int*   flags = (int*)d_ws;                     // 16 words
    float* h     = wsf + 16;                       // 6,400,000
    float* xl    = h  + (long)N_NODES * HC;        // 6,400,000
    float* xr    = xl + (long)N_NODES * HC;        // 6,400,000
    float* prm   = xr + (long)N_NODES * HC;        // 110,000
    int*   eidx  = (int*)(prm + 110000);           // 1,600,000
    int*   off   = eidx + 2 * E_EDGES;             // 50,001
    int*   fill  = off + (N_NODES + 1);            // 50,000
    int*   csr   = fill + N_NODES;                 // 850,000
    // h2/h3 overlay xl (free after conv layers)
    float* h2 = xl;
    float* h3 = xl + (long)N_NODES * DIM;

    // param block offsets (floats)
    float* pWl = prm + 0;        // 3*16384
    float* pWr = prm + 49152;    // 3*16384
    float* pbl = prm + 98304;    // 3*128
    float* pbr = prm + 98688;
    float* patt= prm + 99072;
    float* pcb = prm + 99456;
    float* pW1 = prm + 99840;    // 4096
    float* pb1 = prm + 103936;   // 32
    float* pW2 = prm + 103968;   // 512
    float* pb2 = prm + 104480;   // 16
    float* pW3 = prm + 104496;   // 192
    float* pb3 = prm + 104688;   // 6

    // 1. detect dtypes (deterministic function of pristine inputs)
    k_detect<<<1, 256, 0, stream>>>(d_in[3], d_in[1], flags);

    // 2. normalize inputs to fp32 / int32 scratch
    k_cvt<<<(N_NODES * HC + 255) / 256, 256, 0, stream>>>(d_in[0], h, N_NODES * HC, flags);
    k_cvt<<<(49152 + 255) / 256, 256, 0, stream>>>(d_in[3], pWl, 49152, flags);
    k_cvt<<<(49152 + 255) / 256, 256, 0, stream>>>(d_in[4], pWr, 49152, flags);
    k_cvt<<<2, 256, 0, stream>>>(d_in[5], pbl, 384, flags);
    k_cvt<<<2, 256, 0, stream>>>(d_in[6], pbr, 384, flags);
    k_cvt<<<2, 256, 0, stream>>>(d_in[7], patt, 384, flags);
    k_cvt<<<2, 256, 0, stream>>>(d_in[8], pcb, 384, flags);
    k_cvt<<<16, 256, 0, stream>>>(d_in[9], pW1, 4096, flags);
    k_cvt<<<1, 256, 0, stream>>>(d_in[10], pb1, 32, flags);
    k_cvt<<<2, 256, 0, stream>>>(d_in[11], pW2, 512, flags);
    k_cvt<<<1, 256, 0, stream>>>(d_in[12], pb2, 16, flags);
    k_cvt<<<1, 256, 0, stream>>>(d_in[13], pW3, 192, flags);
    k_cvt<<<1, 256, 0, stream>>>(d_in[14], pb3, 6, flags);
    k_cvti<<<(2 * E_EDGES + 255) / 256, 256, 0, stream>>>(d_in[1], eidx, 2 * E_EDGES, flags);

    // 3. CSR build (dst-sorted incoming edge lists, self-loops appended)
    k_zero<<<(2 * N_NODES + 1 + 255) / 256, 256, 0, stream>>>(off, fill);
    k_hist<<<(EA + 255) / 256, 256, 0, stream>>>(eidx, off);
    k_scan<<<1, 1024, 0, stream>>>(off);
    k_scatter<<<(EA + 255) / 256, 256, 0, stream>>>(eidx, off, fill, csr);

    // 4. three GATv2 layers (h updated in place by k_attn)
    for (int i = 0; i < 3; i++) {
        k_gemm2<<<(N_NODES + GROWS - 1) / GROWS, 128, 0, stream>>>(
            h, pWl + (long)i * HC * HC, pWr + (long)i * HC * HC,
            pbl + (long)i * HC, pbr + (long)i * HC, xl, xr);
        k_attn<<<(N_NODES + 3) / 4, 256, 0, stream>>>(
            xl, xr, off, csr, patt + (long)i * HEADS * DIM, pcb + (long)i * HC, h);
    }

    // 5. MLP head
    k_mlp1<<<(N_NODES + 7) / 8, 256, 0, stream>>>(h, pW1, pb1, h2);
    k_mlp2<<<(N_NODES + 15) / 16, 256, 0, stream>>>(h2, pW2, pb2, h3);

    // 6. outputs
    k_out0<<<(E_EDGES + 255) / 256, 256, 0, stream>>>(h3, eidx, pW3, pb3, d_out, flags);
    k_eout<<<(int)(((long)E_EDGES * 2 * DIM2 + 255) / 256), 256, 0, stream>>>(h3, eidx, d_out, flags);
}

// Round 3
// 998.779 us; speedup vs baseline: 1.4228x; 1.4228x over previous
//
#include <hip/hip_runtime.h>
#include <hip/hip_bf16.h>

typedef __hip_bfloat16 bf16;

#define N_NODES 50000
#define E_EDGES 800000
#define EA (E_EDGES + N_NODES)   // 850000 edges incl self-loops
#define HC 128                   // heads*dim
#define HEADS 4
#define DIM 32
#define DIM2 16
#define NCLS 6
#define SLOPE 0.2f
#define NCHUNK ((N_NODES + 1023) / 1024)   // 49

__device__ __forceinline__ float b2f(bf16 v) { return __bfloat162float(v); }
__device__ __forceinline__ unsigned short f2bfu(float f) {
    bf16 b = __float2bfloat16(f);
    return *(unsigned short*)&b;
}

// ---------------- dtype detector ----------------
// flags[0]=1 -> float inputs (and output) are fp32; 0 -> bf16
// flags[1]=1 -> edge_index is int64; 0 -> int32
__global__ __launch_bounds__(256) void k_detect(const void* wptr, const void* eptr,
                                                int* __restrict__ flags) {
    __shared__ int sb[256], sn[256];
    int tid = threadIdx.x;
    const unsigned short* w = (const unsigned short*)wptr;
    int badf = 0;
    for (int i = tid; i < 4096; i += 256) {
        unsigned v = w[i];
        unsigned ex = (v >> 7) & 0xFF;
        if (v != 0 && (ex < 90 || ex > 150)) badf++;
    }
    const int* ei = (const int*)eptr;
    int nz = 0;
    for (int i = tid; i < 2048; i += 256) {
        if (ei[2 * i + 1] != 0) nz++;
    }
    sb[tid] = badf; sn[tid] = nz;
    __syncthreads();
    for (int ofs = 128; ofs > 0; ofs >>= 1) {
        if (tid < ofs) { sb[tid] += sb[tid + ofs]; sn[tid] += sn[tid + ofs]; }
        __syncthreads();
    }
    if (tid == 0) {
        flags[0] = (sb[0] > 64) ? 1 : 0;   // many wild exponents -> fp32 data
        flags[1] = (sn[0] < 64) ? 1 : 0;   // odd words all zero -> int64 data
    }
}

// ---------------- input normalization to fp32 / int32 ----------------
__global__ void k_cvt(const void* __restrict__ src, float* __restrict__ dst, int n,
                      const int* __restrict__ flags) {
    int i = blockIdx.x * blockDim.x + threadIdx.x;
    if (i >= n) return;
    if (flags[0]) dst[i] = ((const float*)src)[i];
    else          dst[i] = b2f(((const bf16*)src)[i]);
}

__global__ void k_cvti(const void* __restrict__ src, int* __restrict__ dst, int n,
                       const int* __restrict__ flags) {
    int i = blockIdx.x * blockDim.x + threadIdx.x;
    if (i >= n) return;
    int v;
    if (flags[1]) v = (int)((const long long*)src)[i];
    else          v = ((const int*)src)[i];
    if (v < 0) v = 0;
    if (v >= N_NODES) v = N_NODES - 1;
    dst[i] = v;
}

// ---------------- CSR build ----------------
__global__ void k_zero(int* __restrict__ off, int* __restrict__ fill) {
    int i = blockIdx.x * blockDim.x + threadIdx.x;
    if (i <= N_NODES) off[i] = 0;
    if (i < N_NODES) fill[i] = 0;
}

__global__ void k_hist(const int* __restrict__ eidx, int* __restrict__ off) {
    int e = blockIdx.x * blockDim.x + threadIdx.x;
    if (e >= EA) return;
    int dst = (e < E_EDGES) ? eidx[E_EDGES + e] : (e - E_EDGES);
    atomicAdd(&off[dst], 1);
}

// hierarchical exclusive scan: per-chunk scan + partials
__global__ __launch_bounds__(1024) void k_scan1(int* __restrict__ off, int* __restrict__ part) {
    __shared__ int s[1024];
    int tid = threadIdx.x;
    int i = blockIdx.x * 1024 + tid;
    int v = (i < N_NODES) ? off[i] : 0;
    s[tid] = v;
    __syncthreads();
    for (int o = 1; o < 1024; o <<= 1) {
        int t = (tid >= o) ? s[tid - o] : 0;
        __syncthreads();
        s[tid] += t;
        __syncthreads();
    }
    if (i < N_NODES) off[i] = s[tid] - v;          // chunk-local exclusive
    if (tid == 1023) part[blockIdx.x] = s[1023];   // chunk total
}

__global__ __launch_bounds__(64) void k_scan2(int* __restrict__ part) {
    int tid = threadIdx.x;
    int v = (tid < NCHUNK) ? part[tid] : 0;
    int orig = v;
    for (int o = 1; o < 64; o <<= 1) {
        int t = __shfl_up(v, o);
        if (tid >= o) v += t;
    }
    if (tid < NCHUNK) part[tid] = v - orig;        // exclusive scan of partials
}

__global__ __launch_bounds__(1024) void k_scan3(int* __restrict__ off, const int* __restrict__ part) {
    int i = blockIdx.x * 1024 + threadIdx.x;
    if (i < N_NODES) off[i] += part[blockIdx.x];
    if (i == 0) off[N_NODES] = EA;
}

__global__ void k_scatter(const int* __restrict__ eidx, const int* __restrict__ off,
                          int* __restrict__ fill, int* __restrict__ csrsrc) {
    int e = blockIdx.x * blockDim.x + threadIdx.x;
    if (e >= EA) return;
    int src, dst;
    if (e < E_EDGES) { src = eidx[e]; dst = eidx[E_EDGES + e]; }
    else             { src = dst = e - E_EDGES; }
    int pos = off[dst] + atomicAdd(&fill[dst], 1);
    if (pos >= 0 && pos < EA) csrsrc[pos] = src;
}

// ---------------- xl/xr = h @ Wl + bl, h @ Wr + br (all fp32) ----------------
#define GROWS 32
__global__ __launch_bounds__(128) void k_gemm2(
        const float* __restrict__ h,
        const float* __restrict__ Wl, const float* __restrict__ Wr,
        const float* __restrict__ bl, const float* __restrict__ br,
        float* __restrict__ xl, float* __restrict__ xr) {
    __shared__ __align__(16) float hs[GROWS * HC];
    int tid = threadIdx.x;
    long row0 = (long)blockIdx.x * GROWS;
    for (int idx = tid; idx < GROWS * HC; idx += 128) {
        long g = row0 * HC + idx;
        hs[idx] = (g < (long)N_NODES * HC) ? h[g] : 0.f;
    }
    __syncthreads();
    int col = tid;
    float accL[GROWS], accR[GROWS];
#pragma unroll
    for (int r = 0; r < GROWS; r++) { accL[r] = 0.f; accR[r] = 0.f; }
    const float4* hs4 = (const float4*)hs;
    for (int k = 0; k < HC; k += 4) {
        float wl0 = Wl[(k + 0) * HC + col];
        float wl1 = Wl[(k + 1) * HC + col];
        float wl2 = Wl[(k + 2) * HC + col];
        float wl3 = Wl[(k + 3) * HC + col];
        float wr0 = Wr[(k + 0) * HC + col];
        float wr1 = Wr[(k + 1) * HC + col];
        float wr2 = Wr[(k + 2) * HC + col];
        float wr3 = Wr[(k + 3) * HC + col];
#pragma unroll
        for (int r = 0; r < GROWS; r++) {
            float4 hv = hs4[(r * HC + k) >> 2];
            accL[r] += hv.x * wl0 + hv.y * wl1 + hv.z * wl2 + hv.w * wl3;
            accR[r] += hv.x * wr0 + hv.y * wr1 + hv.z * wr2 + hv.w * wr3;
        }
    }
    float blv = bl[col], brv = br[col];
    int nrows = (int)((N_NODES - row0) < GROWS ? (N_NODES - row0) : GROWS);
    for (int r = 0; r < nrows; r++) {
        xl[(row0 + r) * HC + col] = accL[r] + blv;
        xr[(row0 + r) * HC + col] = accR[r] + brv;
    }
}

// ---------------- GATv2 aggregation: one wave/node, single-pass online softmax --
__global__ __launch_bounds__(256) void k_attn(
        const float* __restrict__ xl, const float* __restrict__ xr,
        const int* __restrict__ off, const int* __restrict__ csrsrc,
        const float* __restrict__ att, const float* __restrict__ cb,
        float* __restrict__ hout) {
    int wave = threadIdx.x >> 6;
    int lane = threadIdx.x & 63;
    int node = blockIdx.x * 4 + wave;
    if (node >= N_NODES) return;
    int head = lane >> 4;
    int f0 = 2 * lane;
    float2 xrv = ((const float2*)(xr + (long)node * HC))[lane];
    float a0 = att[head * DIM + (f0 & 31)];
    float a1 = att[head * DIM + ((f0 + 1) & 31)];
    int e0 = off[node], e1 = off[node + 1];
    if (e0 < 0) e0 = 0;
    if (e1 > EA) e1 = EA;

    float m = -1e30f, ssum = 0.f, acc0 = 0.f, acc1 = 0.f;
    int k = e0;
    float2 xlv = make_float2(0.f, 0.f);
    if (k < e1) {
        int s = csrsrc[k];
        xlv = ((const float2*)(xl + (long)s * HC))[lane];
    }
    while (k < e1) {
        float2 cur = xlv;
        int kn = k + 1;
        if (kn < e1) {                        // prefetch next row (wave-uniform branch)
            int s = csrsrc[kn];
            xlv = ((const float2*)(xl + (long)s * HC))[lane];
        }
        float m0 = cur.x + xrv.x, m1 = cur.y + xrv.y;
        float v0 = m0 > 0.f ? m0 : SLOPE * m0;
        float v1 = m1 > 0.f ? m1 : SLOPE * m1;
        float p = v0 * a0 + v1 * a1;
        p += __shfl_xor(p, 1);
        p += __shfl_xor(p, 2);
        p += __shfl_xor(p, 4);
        p += __shfl_xor(p, 8);                // 16-lane head group holds the dot
        float mn = fmaxf(m, p);
        float scale = __expf(m - mn);         // 1 when no new max; 0 on first edge
        float ex = __expf(p - mn);            // <= 1 always
        ssum = ssum * scale + ex;
        acc0 = acc0 * scale + ex * cur.x;
        acc1 = acc1 * scale + ex * cur.y;
        m = mn;
        k = kn;
    }
    float inv = 1.f / (ssum + 1e-16f);
    float o0 = acc0 * inv + cb[f0];
    float o1 = acc1 * inv + cb[f0 + 1];
    hout[(long)node * HC + f0]     = o0 > 0.f ? o0 : 0.f;
    hout[(long)node * HC + f0 + 1] = o1 > 0.f ? o1 : 0.f;
}

// ---------------- h2 = relu(h @ W1 + b1) : [N,128]@[128,32] ----------------
__global__ __launch_bounds__(256) void k_mlp1(
        const float* __restrict__ h, const float* __restrict__ W1,
        const float* __restrict__ b1, float* __restrict__ h2) {
    __shared__ float hs[8 * HC];
    __shared__ float w1s[HC * DIM];
    int tid = threadIdx.x;
    long row0 = (long)blockIdx.x * 8;
    for (int idx = tid; idx < HC * DIM; idx += 256) w1s[idx] = W1[idx];
    for (int idx = tid; idx < 8 * HC; idx += 256) {
        long g = row0 * HC + idx;
        hs[idx] = (g < (long)N_NODES * HC) ? h[g] : 0.f;
    }
    __syncthreads();
    int r = tid >> 5, c = tid & 31;
    float acc = b1[c];
    for (int k = 0; k < HC; k++) acc += hs[r * HC + k] * w1s[k * DIM + c];
    long row = row0 + r;
    if (row < N_NODES) h2[row * DIM + c] = acc > 0.f ? acc : 0.f;
}

// ---------------- h3 = relu(h2 @ W2 + b2) : [N,32]@[32,16] ----------------
__global__ __launch_bounds__(256) void k_mlp2(
        const float* __restrict__ h2, const float* __restrict__ W2,
        const float* __restrict__ b2, float* __restrict__ h3) {
    __shared__ float hs[16 * DIM];
    __shared__ float w2s[DIM * DIM2];
    int tid = threadIdx.x;
    long row0 = (long)blockIdx.x * 16;
    for (int idx = tid; idx < DIM * DIM2; idx += 256) w2s[idx] = W2[idx];
    for (int idx = tid; idx < 16 * DIM; idx += 256) {
        long g = row0 * DIM + idx;
        hs[idx] = (g < (long)N_NODES * DIM) ? h2[g] : 0.f;
    }
    __syncthreads();
    int r = tid >> 4, c = tid & 15;
    float acc = b2[c];
    for (int k = 0; k < DIM; k++) acc += hs[r * DIM + k] * w2s[k * DIM2 + c];
    long row = row0 + r;
    if (row < N_NODES) h3[row * DIM2 + c] = acc > 0.f ? acc : 0.f;
}

// ------- fused head: out0 = concat(h3[src],h3[dst]) @ W3 + b3, eout = concat ----
__global__ __launch_bounds__(256) void k_out(
        const float* __restrict__ h3, const int* __restrict__ eidx,
        const float* __restrict__ W3, const float* __restrict__ b3,
        void* __restrict__ dout, const int* __restrict__ flags) {
    __shared__ float w3s[2 * DIM2 * NCLS];
    __shared__ float bs[NCLS];
    int tid = threadIdx.x;
    if (tid < 2 * DIM2 * NCLS) w3s[tid] = W3[tid];
    if (tid < NCLS) bs[tid] = b3[tid];
    __syncthreads();
    int e = blockIdx.x * 256 + tid;
    if (e >= E_EDGES) return;
    int src = eidx[e], dst = eidx[E_EDGES + e];
    float v[2 * DIM2];
    const float4* ps = (const float4*)(h3 + (long)src * DIM2);
    const float4* pd = (const float4*)(h3 + (long)dst * DIM2);
#pragma unroll
    for (int q = 0; q < 4; q++) {
        float4 t = ps[q];
        v[q * 4 + 0] = t.x; v[q * 4 + 1] = t.y; v[q * 4 + 2] = t.z; v[q * 4 + 3] = t.w;
    }
#pragma unroll
    for (int q = 0; q < 4; q++) {
        float4 t = pd[q];
        v[16 + q * 4 + 0] = t.x; v[16 + q * 4 + 1] = t.y; v[16 + q * 4 + 2] = t.z; v[16 + q * 4 + 3] = t.w;
    }
    float o[NCLS];
#pragma unroll
    for (int j = 0; j < NCLS; j++) {
        float acc = bs[j];
#pragma unroll
        for (int k = 0; k < 2 * DIM2; k++) acc += v[k] * w3s[k * NCLS + j];
        o[j] = acc;
    }
    if (flags[0]) {
        float* out0 = (float*)dout;
#pragma unroll
        for (int j = 0; j < NCLS; j++) out0[(long)e * NCLS + j] = o[j];
        float4* eo = (float4*)((float*)dout + (long)E_EDGES * NCLS) + (long)e * 8;
#pragma unroll
        for (int q = 0; q < 8; q++)
            eo[q] = make_float4(v[q * 4], v[q * 4 + 1], v[q * 4 + 2], v[q * 4 + 3]);
    } else {
        bf16* out0 = (bf16*)dout;
#pragma unroll
        for (int j = 0; j < NCLS; j++) out0[(long)e * NCLS + j] = __float2bfloat16(o[j]);
        uint4* eo = (uint4*)((bf16*)dout + (long)E_EDGES * NCLS) + (long)e * 4;
#pragma unroll
        for (int q = 0; q < 4; q++) {
            uint4 w;
            w.x = (unsigned)f2bfu(v[q * 8 + 0]) | ((unsigned)f2bfu(v[q * 8 + 1]) << 16);
            w.y = (unsigned)f2bfu(v[q * 8 + 2]) | ((unsigned)f2bfu(v[q * 8 + 3]) << 16);
            w.z = (unsigned)f2bfu(v[q * 8 + 4]) | ((unsigned)f2bfu(v[q * 8 + 5]) << 16);
            w.w = (unsigned)f2bfu(v[q * 8 + 6]) | ((unsigned)f2bfu(v[q * 8 + 7]) << 16);
            eo[q] = w;
        }
    }
}

extern "C" void kernel_launch(void* const* d_in, const int* in_sizes, int n_in,
                              void* d_out, int out_size, void* d_ws, size_t ws_size,
                              hipStream_t stream) {
    // ---- workspace layout (4-byte word offsets) ----
    float* wsf   = (float*)d_ws;
    int*   flags = (int*)d_ws;                     // 16 words
    float* h     = wsf + 16;                       // 6,400,000
    float* xl    = h  + (long)N_NODES * HC;        // 6,400,000
    float* xr    = xl + (long)N_NODES * HC;        // 6,400,000
    float* prm   = xr + (long)N_NODES * HC;        // 110,000
    int*   eidx  = (int*)(prm + 110000);           // 1,600,000
    int*   off   = eidx + 2 * E_EDGES;             // 50,001
    int*   fill  = off + (N_NODES + 1);            // 50,000
    int*   csr   = fill + N_NODES;                 // 850,000
    int*   part  = csr + EA;                       // 64
    // h2/h3 overlay xl (free after conv layers)
    float* h2 = xl;
    float* h3 = xl + (long)N_NODES * DIM;

    // param block offsets (floats)
    float* pWl = prm + 0;        // 3*16384
    float* pWr = prm + 49152;    // 3*16384
    float* pbl = prm + 98304;    // 3*128
    float* pbr = prm + 98688;
    float* patt= prm + 99072;
    float* pcb = prm + 99456;
    float* pW1 = prm + 99840;    // 4096
    float* pb1 = prm + 103936;   // 32
    float* pW2 = prm + 103968;   // 512
    float* pb2 = prm + 104480;   // 16
    float* pW3 = prm + 104496;   // 192
    float* pb3 = prm + 104688;   // 6

    // 1. detect dtypes (deterministic function of pristine inputs)
    k_detect<<<1, 256, 0, stream>>>(d_in[3], d_in[1], flags);

    // 2. normalize inputs to fp32 / int32 scratch
    k_cvt<<<(N_NODES * HC + 255) / 256, 256, 0, stream>>>(d_in[0], h, N_NODES * HC, flags);
    k_cvt<<<(49152 + 255) / 256, 256, 0, stream>>>(d_in[3], pWl, 49152, flags);
    k_cvt<<<(49152 + 255) / 256, 256, 0, stream>>>(d_in[4], pWr, 49152, flags);
    k_cvt<<<2, 256, 0, stream>>>(d_in[5], pbl, 384, flags);
    k_cvt<<<2, 256, 0, stream>>>(d_in[6], pbr, 384, flags);
    k_cvt<<<2, 256, 0, stream>>>(d_in[7], patt, 384, flags);
    k_cvt<<<2, 256, 0, stream>>>(d_in[8], pcb, 384, flags);
    k_cvt<<<16, 256, 0, stream>>>(d_in[9], pW1, 4096, flags);
    k_cvt<<<1, 256, 0, stream>>>(d_in[10], pb1, 32, flags);
    k_cvt<<<2, 256, 0, stream>>>(d_in[11], pW2, 512, flags);
    k_cvt<<<1, 256, 0, stream>>>(d_in[12], pb2, 16, flags);
    k_cvt<<<1, 256, 0, stream>>>(d_in[13], pW3, 192, flags);
    k_cvt<<<1, 256, 0, stream>>>(d_in[14], pb3, 6, flags);
    k_cvti<<<(2 * E_EDGES + 255) / 256, 256, 0, stream>>>(d_in[1], eidx, 2 * E_EDGES, flags);

    // 3. CSR build (dst-sorted incoming edge lists, self-loops appended)
    k_zero<<<(2 * N_NODES + 1 + 255) / 256, 256, 0, stream>>>(off, fill);
    k_hist<<<(EA + 255) / 256, 256, 0, stream>>>(eidx, off);
    k_scan1<<<NCHUNK, 1024, 0, stream>>>(off, part);
    k_scan2<<<1, 64, 0, stream>>>(part);
    k_scan3<<<NCHUNK, 1024, 0, stream>>>(off, part);
    k_scatter<<<(EA + 255) / 256, 256, 0, stream>>>(eidx, off, fill, csr);

    // 4. three GATv2 layers (h updated in place by k_attn)
    for (int i = 0; i < 3; i++) {
        k_gemm2<<<(N_NODES + GROWS - 1) / GROWS, 128, 0, stream>>>(
            h, pWl + (long)i * HC * HC, pWr + (long)i * HC * HC,
            pbl + (long)i * HC, pbr + (long)i * HC, xl, xr);
        k_attn<<<(N_NODES + 3) / 4, 256, 0, stream>>>(
            xl, xr, off, csr, patt + (long)i * HEADS * DIM, pcb + (long)i * HC, h);
    }

    // 5. MLP head
    k_mlp1<<<(N_NODES + 7) / 8, 256, 0, stream>>>(h, pW1, pb1, h2);
    k_mlp2<<<(N_NODES + 15) / 16, 256, 0, stream>>>(h2, pW2, pb2, h3);

    // 6. fused outputs (single gather of h3 rows)
    k_out<<<(E_EDGES + 255) / 256, 256, 0, stream>>>(h3, eidx, pW3, pb3, d_out, flags);
}

// Round 4
// 965.269 us; speedup vs baseline: 1.4722x; 1.0347x over previous
//
#include <hip/hip_runtime.h>
#include <hip/hip_bf16.h>

typedef __hip_bfloat16 bf16;

#define N_NODES 50000
#define E_EDGES 800000
#define EA (E_EDGES + N_NODES)   // 850000 edges incl self-loops
#define HC 128                   // heads*dim
#define HEADS 4
#define DIM 32
#define DIM2 16
#define NCLS 6
#define SLOPE 0.2f
#define NCHUNK ((N_NODES + 1023) / 1024)   // 49

__device__ __forceinline__ float b2f(bf16 v) { return __bfloat162float(v); }
__device__ __forceinline__ unsigned short f2bfu(float f) {
    bf16 b = __float2bfloat16(f);
    return *(unsigned short*)&b;
}

// ---------------- dtype detector ----------------
// flags[0]=1 -> float inputs (and output) are fp32; 0 -> bf16
// flags[1]=1 -> edge_index is int64; 0 -> int32
__global__ __launch_bounds__(256) void k_detect(const void* wptr, const void* eptr,
                                                int* __restrict__ flags) {
    __shared__ int sb[256], sn[256];
    int tid = threadIdx.x;
    const unsigned short* w = (const unsigned short*)wptr;
    int badf = 0;
    for (int i = tid; i < 4096; i += 256) {
        unsigned v = w[i];
        unsigned ex = (v >> 7) & 0xFF;
        if (v != 0 && (ex < 90 || ex > 150)) badf++;
    }
    const int* ei = (const int*)eptr;
    int nz = 0;
    for (int i = tid; i < 2048; i += 256) {
        if (ei[2 * i + 1] != 0) nz++;
    }
    sb[tid] = badf; sn[tid] = nz;
    __syncthreads();
    for (int ofs = 128; ofs > 0; ofs >>= 1) {
        if (tid < ofs) { sb[tid] += sb[tid + ofs]; sn[tid] += sn[tid + ofs]; }
        __syncthreads();
    }
    if (tid == 0) {
        flags[0] = (sb[0] > 64) ? 1 : 0;   // many wild exponents -> fp32 data
        flags[1] = (sn[0] < 64) ? 1 : 0;   // odd words all zero -> int64 data
    }
}

// ---------------- input normalization to fp32 / int32 ----------------
__global__ void k_cvt(const void* __restrict__ src, float* __restrict__ dst, int n,
                      const int* __restrict__ flags) {
    int i = blockIdx.x * blockDim.x + threadIdx.x;
    if (i >= n) return;
    if (flags[0]) dst[i] = ((const float*)src)[i];
    else          dst[i] = b2f(((const bf16*)src)[i]);
}

__global__ void k_cvti(const void* __restrict__ src, int* __restrict__ dst, int n,
                       const int* __restrict__ flags) {
    int i = blockIdx.x * blockDim.x + threadIdx.x;
    if (i >= n) return;
    int v;
    if (flags[1]) v = (int)((const long long*)src)[i];
    else          v = ((const int*)src)[i];
    if (v < 0) v = 0;
    if (v >= N_NODES) v = N_NODES - 1;
    dst[i] = v;
}

// ---------------- CSR build ----------------
__global__ void k_zero(int* __restrict__ off, int* __restrict__ fill) {
    int i = blockIdx.x * blockDim.x + threadIdx.x;
    if (i <= N_NODES) off[i] = 0;
    if (i < N_NODES) fill[i] = 0;
}

__global__ void k_hist(const int* __restrict__ eidx, int* __restrict__ off) {
    int e = blockIdx.x * blockDim.x + threadIdx.x;
    if (e >= EA) return;
    int dst = (e < E_EDGES) ? eidx[E_EDGES + e] : (e - E_EDGES);
    atomicAdd(&off[dst], 1);
}

// hierarchical exclusive scan: per-chunk scan + partials
__global__ __launch_bounds__(1024) void k_scan1(int* __restrict__ off, int* __restrict__ part) {
    __shared__ int s[1024];
    int tid = threadIdx.x;
    int i = blockIdx.x * 1024 + tid;
    int v = (i < N_NODES) ? off[i] : 0;
    s[tid] = v;
    __syncthreads();
    for (int o = 1; o < 1024; o <<= 1) {
        int t = (tid >= o) ? s[tid - o] : 0;
        __syncthreads();
        s[tid] += t;
        __syncthreads();
    }
    if (i < N_NODES) off[i] = s[tid] - v;          // chunk-local exclusive
    if (tid == 1023) part[blockIdx.x] = s[1023];   // chunk total
}

__global__ __launch_bounds__(64) void k_scan2(int* __restrict__ part) {
    int tid = threadIdx.x;
    int v = (tid < NCHUNK) ? part[tid] : 0;
    int orig = v;
    for (int o = 1; o < 64; o <<= 1) {
        int t = __shfl_up(v, o);
        if (tid >= o) v += t;
    }
    if (tid < NCHUNK) part[tid] = v - orig;        // exclusive scan of partials
}

__global__ __launch_bounds__(1024) void k_scan3(int* __restrict__ off, const int* __restrict__ part) {
    int i = blockIdx.x * 1024 + threadIdx.x;
    if (i < N_NODES) off[i] += part[blockIdx.x];
    if (i == 0) off[N_NODES] = EA;
}

__global__ void k_scatter(const int* __restrict__ eidx, const int* __restrict__ off,
                          int* __restrict__ fill, int* __restrict__ csrsrc) {
    int e = blockIdx.x * blockDim.x + threadIdx.x;
    if (e >= EA) return;
    int src, dst;
    if (e < E_EDGES) { src = eidx[e]; dst = eidx[E_EDGES + e]; }
    else             { src = dst = e - E_EDGES; }
    int pos = off[dst] + atomicAdd(&fill[dst], 1);
    if (pos >= 0 && pos < EA) csrsrc[pos] = src;
}

// ------- xl(bf16-packed)/xr(fp32) = h @ Wl + bl, h @ Wr + br ----------------
#define GROWS 32
__global__ __launch_bounds__(128) void k_gemm2(
        const float* __restrict__ h,
        const float* __restrict__ Wl, const float* __restrict__ Wr,
        const float* __restrict__ bl, const float* __restrict__ br,
        unsigned* __restrict__ xlbf, float* __restrict__ xr) {
    __shared__ __align__(16) float hs[GROWS * HC];
    int tid = threadIdx.x;
    long row0 = (long)blockIdx.x * GROWS;
    for (int idx = tid; idx < GROWS * HC; idx += 128) {
        long g = row0 * HC + idx;
        hs[idx] = (g < (long)N_NODES * HC) ? h[g] : 0.f;
    }
    __syncthreads();
    int col = tid;
    float accL[GROWS], accR[GROWS];
#pragma unroll
    for (int r = 0; r < GROWS; r++) { accL[r] = 0.f; accR[r] = 0.f; }
    const float4* hs4 = (const float4*)hs;
    for (int k = 0; k < HC; k += 4) {
        float wl0 = Wl[(k + 0) * HC + col];
        float wl1 = Wl[(k + 1) * HC + col];
        float wl2 = Wl[(k + 2) * HC + col];
        float wl3 = Wl[(k + 3) * HC + col];
        float wr0 = Wr[(k + 0) * HC + col];
        float wr1 = Wr[(k + 1) * HC + col];
        float wr2 = Wr[(k + 2) * HC + col];
        float wr3 = Wr[(k + 3) * HC + col];
#pragma unroll
        for (int r = 0; r < GROWS; r++) {
            float4 hv = hs4[(r * HC + k) >> 2];
            accL[r] += hv.x * wl0 + hv.y * wl1 + hv.z * wl2 + hv.w * wl3;
            accR[r] += hv.x * wr0 + hv.y * wr1 + hv.z * wr2 + hv.w * wr3;
        }
    }
    float blv = bl[col], brv = br[col];
    int nrows = (int)((N_NODES - row0) < GROWS ? (N_NODES - row0) : GROWS);
    for (int r = 0; r < nrows; r++) {
        float vL = accL[r] + blv;
        float vP = __shfl_xor(vL, 1);          // partner column's value (lane pair)
        if ((col & 1) == 0)
            xlbf[(row0 + r) * (HC / 2) + (col >> 1)] =
                (unsigned)f2bfu(vL) | ((unsigned)f2bfu(vP) << 16);
        xr[(row0 + r) * HC + col] = accR[r] + brv;
    }
}

// --------- GATv2 aggregation: one wave/node, online softmax, bf16 gather -------
__global__ __launch_bounds__(256) void k_attn(
        const unsigned* __restrict__ xlbf, const float* __restrict__ xr,
        const int* __restrict__ off, const int* __restrict__ csrsrc,
        const float* __restrict__ att, const float* __restrict__ cb,
        float* __restrict__ hout) {
    int wave = threadIdx.x >> 6;
    int lane = threadIdx.x & 63;
    int node = blockIdx.x * 4 + wave;
    if (node >= N_NODES) return;
    int head = lane >> 4;
    int f0 = 2 * lane;
    float2 xrv = ((const float2*)(xr + (long)node * HC))[lane];
    float a0 = att[head * DIM + (f0 & 31)];
    float a1 = att[head * DIM + ((f0 + 1) & 31)];
    int e0 = off[node], e1 = off[node + 1];
    if (e0 < 0) e0 = 0;
    if (e1 > EA) e1 = EA;
    if (e1 <= e0) { // can't happen (self-loop), but stay safe
        hout[(long)node * HC + f0] = 0.f;
        hout[(long)node * HC + f0 + 1] = 0.f;
        return;
    }

    // software pipeline, 2 gathers in flight
    int klast = e1 - 1;
    int s0 = csrsrc[e0];
    int s1 = csrsrc[(e0 + 1 < e1) ? e0 + 1 : klast];
    unsigned u0 = xlbf[(long)s0 * (HC / 2) + lane];
    unsigned u1 = xlbf[(long)s1 * (HC / 2) + lane];

    float m = -1e30f, ssum = 0.f, acc0 = 0.f, acc1 = 0.f;
    for (int k = e0; k < e1; k++) {
        unsigned cur = u0;
        u0 = u1;
        int kp = (k + 2 < e1) ? k + 2 : klast;
        int sp = csrsrc[kp];
        u1 = xlbf[(long)sp * (HC / 2) + lane];

        float x0 = __uint_as_float(cur << 16);
        float x1 = __uint_as_float(cur & 0xffff0000u);
        float m0 = x0 + xrv.x, m1 = x1 + xrv.y;
        float v0 = m0 > 0.f ? m0 : SLOPE * m0;
        float v1 = m1 > 0.f ? m1 : SLOPE * m1;
        float p = v0 * a0 + v1 * a1;
        p += __shfl_xor(p, 1);
        p += __shfl_xor(p, 2);
        p += __shfl_xor(p, 4);
        p += __shfl_xor(p, 8);                // 16-lane head group holds the dot
        float mn = fmaxf(m, p);
        float scale = __expf(m - mn);
        float ex = __expf(p - mn);            // <= 1 always
        ssum = ssum * scale + ex;
        acc0 = acc0 * scale + ex * x0;
        acc1 = acc1 * scale + ex * x1;
        m = mn;
    }
    float inv = 1.f / (ssum + 1e-16f);
    float o0 = acc0 * inv + cb[f0];
    float o1 = acc1 * inv + cb[f0 + 1];
    hout[(long)node * HC + f0]     = o0 > 0.f ? o0 : 0.f;
    hout[(long)node * HC + f0 + 1] = o1 > 0.f ? o1 : 0.f;
}

// ---------------- h2 = relu(h @ W1 + b1) : [N,128]@[128,32] ----------------
__global__ __launch_bounds__(256) void k_mlp1(
        const float* __restrict__ h, const float* __restrict__ W1,
        const float* __restrict__ b1, float* __restrict__ h2) {
    __shared__ float hs[8 * HC];
    __shared__ float w1s[HC * DIM];
    int tid = threadIdx.x;
    long row0 = (long)blockIdx.x * 8;
    for (int idx = tid; idx < HC * DIM; idx += 256) w1s[idx] = W1[idx];
    for (int idx = tid; idx < 8 * HC; idx += 256) {
        long g = row0 * HC + idx;
        hs[idx] = (g < (long)N_NODES * HC) ? h[g] : 0.f;
    }
    __syncthreads();
    int r = tid >> 5, c = tid & 31;
    float acc = b1[c];
    for (int k = 0; k < HC; k++) acc += hs[r * HC + k] * w1s[k * DIM + c];
    long row = row0 + r;
    if (row < N_NODES) h2[row * DIM + c] = acc > 0.f ? acc : 0.f;
}

// ---------------- h3 = relu(h2 @ W2 + b2) : [N,32]@[32,16] ----------------
__global__ __launch_bounds__(256) void k_mlp2(
        const float* __restrict__ h2, const float* __restrict__ W2,
        const float* __restrict__ b2, float* __restrict__ h3) {
    __shared__ float hs[16 * DIM];
    __shared__ float w2s[DIM * DIM2];
    int tid = threadIdx.x;
    long row0 = (long)blockIdx.x * 16;
    for (int idx = tid; idx < DIM * DIM2; idx += 256) w2s[idx] = W2[idx];
    for (int idx = tid; idx < 16 * DIM; idx += 256) {
        long g = row0 * DIM + idx;
        hs[idx] = (g < (long)N_NODES * DIM) ? h2[g] : 0.f;
    }
    __syncthreads();
    int r = tid >> 4, c = tid & 15;
    float acc = b2[c];
    for (int k = 0; k < DIM; k++) acc += hs[r * DIM + k] * w2s[k * DIM2 + c];
    long row = row0 + r;
    if (row < N_NODES) h3[row * DIM2 + c] = acc > 0.f ? acc : 0.f;
}

// ------- fused head: out0 = concat(h3[src],h3[dst]) @ W3 + b3, eout = concat ----
__global__ __launch_bounds__(256) void k_out(
        const float* __restrict__ h3, const int* __restrict__ eidx,
        const float* __restrict__ W3, const float* __restrict__ b3,
        void* __restrict__ dout, const int* __restrict__ flags) {
    __shared__ float w3s[2 * DIM2 * NCLS];
    __shared__ float bs[NCLS];
    int tid = threadIdx.x;
    if (tid < 2 * DIM2 * NCLS) w3s[tid] = W3[tid];
    if (tid < NCLS) bs[tid] = b3[tid];
    __syncthreads();
    int e = blockIdx.x * 256 + tid;
    if (e >= E_EDGES) return;
    int src = eidx[e], dst = eidx[E_EDGES + e];
    float v[2 * DIM2];
    const float4* ps = (const float4*)(h3 + (long)src * DIM2);
    const float4* pd = (const float4*)(h3 + (long)dst * DIM2);
#pragma unroll
    for (int q = 0; q < 4; q++) {
        float4 t = ps[q];
        v[q * 4 + 0] = t.x; v[q * 4 + 1] = t.y; v[q * 4 + 2] = t.z; v[q * 4 + 3] = t.w;
    }
#pragma unroll
    for (int q = 0; q < 4; q++) {
        float4 t = pd[q];
        v[16 + q * 4 + 0] = t.x; v[16 + q * 4 + 1] = t.y; v[16 + q * 4 + 2] = t.z; v[16 + q * 4 + 3] = t.w;
    }
    float o[NCLS];
#pragma unroll
    for (int j = 0; j < NCLS; j++) {
        float acc = bs[j];
#pragma unroll
        for (int k = 0; k < 2 * DIM2; k++) acc += v[k] * w3s[k * NCLS + j];
        o[j] = acc;
    }
    if (flags[0]) {
        float* out0 = (float*)dout;
#pragma unroll
        for (int j = 0; j < NCLS; j++) out0[(long)e * NCLS + j] = o[j];
        float4* eo = (float4*)((float*)dout + (long)E_EDGES * NCLS) + (long)e * 8;
#pragma unroll
        for (int q = 0; q < 8; q++)
            eo[q] = make_float4(v[q * 4], v[q * 4 + 1], v[q * 4 + 2], v[q * 4 + 3]);
    } else {
        bf16* out0 = (bf16*)dout;
#pragma unroll
        for (int j = 0; j < NCLS; j++) out0[(long)e * NCLS + j] = __float2bfloat16(o[j]);
        uint4* eo = (uint4*)((bf16*)dout + (long)E_EDGES * NCLS) + (long)e * 4;
#pragma unroll
        for (int q = 0; q < 4; q++) {
            uint4 w;
            w.x = (unsigned)f2bfu(v[q * 8 + 0]) | ((unsigned)f2bfu(v[q * 8 + 1]) << 16);
            w.y = (unsigned)f2bfu(v[q * 8 + 2]) | ((unsigned)f2bfu(v[q * 8 + 3]) << 16);
            w.z = (unsigned)f2bfu(v[q * 8 + 4]) | ((unsigned)f2bfu(v[q * 8 + 5]) << 16);
            w.w = (unsigned)f2bfu(v[q * 8 + 6]) | ((unsigned)f2bfu(v[q * 8 + 7]) << 16);
            eo[q] = w;
        }
    }
}

extern "C" void kernel_launch(void* const* d_in, const int* in_sizes, int n_in,
                              void* d_out, int out_size, void* d_ws, size_t ws_size,
                              hipStream_t stream) {
    // ---- workspace layout (4-byte word offsets) ----
    float* wsf   = (float*)d_ws;
    int*   flags = (int*)d_ws;                     // 16 words
    float* h     = wsf + 16;                       // 6,400,000
    float* xl    = h  + (long)N_NODES * HC;        // 6,400,000 words reserved (xlbf uses half)
    float* xr    = xl + (long)N_NODES * HC;        // 6,400,000
    float* prm   = xr + (long)N_NODES * HC;        // 110,000
    int*   eidx  = (int*)(prm + 110000);           // 1,600,000
    int*   off   = eidx + 2 * E_EDGES;             // 50,001
    int*   fill  = off + (N_NODES + 1);            // 50,000
    int*   csr   = fill + N_NODES;                 // 850,000
    int*   part  = csr + EA;                       // 64
    unsigned* xlbf = (unsigned*)xl;                // N*64 packed bf16x2
    // h2/h3 overlay the xl slot (free after conv layers)
    float* h2 = xl;
    float* h3 = xl + (long)N_NODES * DIM;

    // param block offsets (floats)
    float* pWl = prm + 0;        // 3*16384
    float* pWr = prm + 49152;    // 3*16384
    float* pbl = prm + 98304;    // 3*128
    float* pbr = prm + 98688;
    float* patt= prm + 99072;
    float* pcb = prm + 99456;
    float* pW1 = prm + 99840;    // 4096
    float* pb1 = prm + 103936;   // 32
    float* pW2 = prm + 103968;   // 512
    float* pb2 = prm + 104480;   // 16
    float* pW3 = prm + 104496;   // 192
    float* pb3 = prm + 104688;   // 6

    // 1. detect dtypes (deterministic function of pristine inputs)
    k_detect<<<1, 256, 0, stream>>>(d_in[3], d_in[1], flags);

    // 2. normalize inputs to fp32 / int32 scratch
    k_cvt<<<(N_NODES * HC + 255) / 256, 256, 0, stream>>>(d_in[0], h, N_NODES * HC, flags);
    k_cvt<<<(49152 + 255) / 256, 256, 0, stream>>>(d_in[3], pWl, 49152, flags);
    k_cvt<<<(49152 + 255) / 256, 256, 0, stream>>>(d_in[4], pWr, 49152, flags);
    k_cvt<<<2, 256, 0, stream>>>(d_in[5], pbl, 384, flags);
    k_cvt<<<2, 256, 0, stream>>>(d_in[6], pbr, 384, flags);
    k_cvt<<<2, 256, 0, stream>>>(d_in[7], patt, 384, flags);
    k_cvt<<<2, 256, 0, stream>>>(d_in[8], pcb, 384, flags);
    k_cvt<<<16, 256, 0, stream>>>(d_in[9], pW1, 4096, flags);
    k_cvt<<<1, 256, 0, stream>>>(d_in[10], pb1, 32, flags);
    k_cvt<<<2, 256, 0, stream>>>(d_in[11], pW2, 512, flags);
    k_cvt<<<1, 256, 0, stream>>>(d_in[12], pb2, 16, flags);
    k_cvt<<<1, 256, 0, stream>>>(d_in[13], pW3, 192, flags);
    k_cvt<<<1, 256, 0, stream>>>(d_in[14], pb3, 6, flags);
    k_cvti<<<(2 * E_EDGES + 255) / 256, 256, 0, stream>>>(d_in[1], eidx, 2 * E_EDGES, flags);

    // 3. CSR build (dst-sorted incoming edge lists, self-loops appended)
    k_zero<<<(2 * N_NODES + 1 + 255) / 256, 256, 0, stream>>>(off, fill);
    k_hist<<<(EA + 255) / 256, 256, 0, stream>>>(eidx, off);
    k_scan1<<<NCHUNK, 1024, 0, stream>>>(off, part);
    k_scan2<<<1, 64, 0, stream>>>(part);
    k_scan3<<<NCHUNK, 1024, 0, stream>>>(off, part);
    k_scatter<<<(EA + 255) / 256, 256, 0, stream>>>(eidx, off, fill, csr);

    // 4. three GATv2 layers (h updated in place by k_attn)
    for (int i = 0; i < 3; i++) {
        k_gemm2<<<(N_NODES + GROWS - 1) / GROWS, 128, 0, stream>>>(
            h, pWl + (long)i * HC * HC, pWr + (long)i * HC * HC,
            pbl + (long)i * HC, pbr + (long)i * HC, xlbf, xr);
        k_attn<<<(N_NODES + 3) / 4, 256, 0, stream>>>(
            xlbf, xr, off, csr, patt + (long)i * HEADS * DIM, pcb + (long)i * HC, h);
    }

    // 5. MLP head
    k_mlp1<<<(N_NODES + 7) / 8, 256, 0, stream>>>(h, pW1, pb1, h2);
    k_mlp2<<<(N_NODES + 15) / 16, 256, 0, stream>>>(h2, pW2, pb2, h3);

    // 6. fused outputs (single gather of h3 rows)
    k_out<<<(E_EDGES + 255) / 256, 256, 0, stream>>>(h3, eidx, pW3, pb3, d_out, flags);
}

// Round 5
// 760.935 us; speedup vs baseline: 1.8675x; 1.2685x over previous
//
#include <hip/hip_runtime.h>
#include <hip/hip_bf16.h>

typedef __hip_bfloat16 bf16;

#define N_NODES 50000
#define E_EDGES 800000
#define EA (E_EDGES + N_NODES)   // 850000 edges incl self-loops
#define HC 128                   // heads*dim
#define HEADS 4
#define DIM 32
#define DIM2 16
#define NCLS 6
#define SLOPE 0.2f
#define NCHUNK ((N_NODES + 1023) / 1024)   // 49
#define XN (N_NODES * HC)                  // 6,400,000

__device__ __forceinline__ float b2f(bf16 v) { return __bfloat162float(v); }
__device__ __forceinline__ unsigned short f2bfu(float f) {
    bf16 b = __float2bfloat16(f);
    return *(unsigned short*)&b;
}

// ---------------- dtype detector ----------------
// flags[0]=1 -> float inputs (and output) are fp32; 0 -> bf16
// flags[1]=1 -> edge_index is int64; 0 -> int32
__global__ __launch_bounds__(256) void k_detect(const void* wptr, const void* eptr,
                                                int* __restrict__ flags) {
    __shared__ int sb[256], sn[256];
    int tid = threadIdx.x;
    const unsigned short* w = (const unsigned short*)wptr;
    int badf = 0;
    for (int i = tid; i < 4096; i += 256) {
        unsigned v = w[i];
        unsigned ex = (v >> 7) & 0xFF;
        if (v != 0 && (ex < 90 || ex > 150)) badf++;
    }
    const int* ei = (const int*)eptr;
    int nz = 0;
    for (int i = tid; i < 2048; i += 256) {
        if (ei[2 * i + 1] != 0) nz++;
    }
    sb[tid] = badf; sn[tid] = nz;
    __syncthreads();
    for (int ofs = 128; ofs > 0; ofs >>= 1) {
        if (tid < ofs) { sb[tid] += sb[tid + ofs]; sn[tid] += sn[tid + ofs]; }
        __syncthreads();
    }
    if (tid == 0) {
        flags[0] = (sb[0] > 64) ? 1 : 0;   // many wild exponents -> fp32 data
        flags[1] = (sn[0] < 64) ? 1 : 0;   // odd words all zero -> int64 data
    }
}

// ---------- single fused conversion of x + all params to fp32 scratch ----------
__global__ void k_cvt_all(const void* sx, const void* sWl, const void* sWr,
                          const void* sbl, const void* sbr, const void* satt,
                          const void* scb, const void* sW1, const void* sb1,
                          const void* sW2, const void* sb2, const void* sW3,
                          const void* sb3,
                          float* __restrict__ h, float* __restrict__ prm,
                          const int* __restrict__ flags) {
    int i = blockIdx.x * blockDim.x + threadIdx.x;
    if (i >= XN + 104694) return;
    const void* src; float* dst; int off;
    if (i < XN) { src = sx; dst = h; off = i; }
    else {
        int j = i - XN;
        if      (j < 49152)  { src = sWl;  dst = prm;           off = j; }
        else if (j < 98304)  { src = sWr;  dst = prm + 49152;   off = j - 49152; }
        else if (j < 98688)  { src = sbl;  dst = prm + 98304;   off = j - 98304; }
        else if (j < 99072)  { src = sbr;  dst = prm + 98688;   off = j - 98688; }
        else if (j < 99456)  { src = satt; dst = prm + 99072;   off = j - 99072; }
        else if (j < 99840)  { src = scb;  dst = prm + 99456;   off = j - 99456; }
        else if (j < 103936) { src = sW1;  dst = prm + 99840;   off = j - 99840; }
        else if (j < 103968) { src = sb1;  dst = prm + 103936;  off = j - 103936; }
        else if (j < 104480) { src = sW2;  dst = prm + 103968;  off = j - 103968; }
        else if (j < 104496) { src = sb2;  dst = prm + 104480;  off = j - 104480; }
        else if (j < 104688) { src = sW3;  dst = prm + 104496;  off = j - 104496; }
        else                 { src = sb3;  dst = prm + 104688;  off = j - 104688; }
    }
    float v = flags[0] ? ((const float*)src)[off] : b2f(((const bf16*)src)[off]);
    dst[off] = v;
}

__global__ void k_cvti(const void* __restrict__ src, int* __restrict__ dst, int n,
                       const int* __restrict__ flags) {
    int i = blockIdx.x * blockDim.x + threadIdx.x;
    if (i >= n) return;
    int v;
    if (flags[1]) v = (int)((const long long*)src)[i];
    else          v = ((const int*)src)[i];
    if (v < 0) v = 0;
    if (v >= N_NODES) v = N_NODES - 1;
    dst[i] = v;
}

// ---------------- CSR build ----------------
__global__ void k_zero(int* __restrict__ off, int* __restrict__ fill) {
    int i = blockIdx.x * blockDim.x + threadIdx.x;
    if (i <= N_NODES) off[i] = 0;
    if (i < N_NODES) fill[i] = 0;
}

__global__ void k_hist(const int* __restrict__ eidx, int* __restrict__ off) {
    int e = blockIdx.x * blockDim.x + threadIdx.x;
    if (e >= EA) return;
    int dst = (e < E_EDGES) ? eidx[E_EDGES + e] : (e - E_EDGES);
    atomicAdd(&off[dst], 1);
}

// hierarchical exclusive scan: per-chunk scan + partials
__global__ __launch_bounds__(1024) void k_scan1(int* __restrict__ off, int* __restrict__ part) {
    __shared__ int s[1024];
    int tid = threadIdx.x;
    int i = blockIdx.x * 1024 + tid;
    int v = (i < N_NODES) ? off[i] : 0;
    s[tid] = v;
    __syncthreads();
    for (int o = 1; o < 1024; o <<= 1) {
        int t = (tid >= o) ? s[tid - o] : 0;
        __syncthreads();
        s[tid] += t;
        __syncthreads();
    }
    if (i < N_NODES) off[i] = s[tid] - v;          // chunk-local exclusive
    if (tid == 1023) part[blockIdx.x] = s[1023];   // chunk total
}

__global__ __launch_bounds__(64) void k_scan2(int* __restrict__ part) {
    int tid = threadIdx.x;
    int v = (tid < NCHUNK) ? part[tid] : 0;
    int orig = v;
    for (int o = 1; o < 64; o <<= 1) {
        int t = __shfl_up(v, o);
        if (tid >= o) v += t;
    }
    if (tid < NCHUNK) part[tid] = v - orig;        // exclusive scan of partials
}

__global__ __launch_bounds__(1024) void k_scan3(int* __restrict__ off, const int* __restrict__ part) {
    int i = blockIdx.x * 1024 + threadIdx.x;
    if (i < N_NODES) off[i] += part[blockIdx.x];
    if (i == 0) off[N_NODES] = EA;
}

__global__ void k_scatter(const int* __restrict__ eidx, const int* __restrict__ off,
                          int* __restrict__ fill, int* __restrict__ csrsrc) {
    int e = blockIdx.x * blockDim.x + threadIdx.x;
    if (e >= EA) return;
    int src, dst;
    if (e < E_EDGES) { src = eidx[e]; dst = eidx[E_EDGES + e]; }
    else             { src = dst = e - E_EDGES; }
    int pos = off[dst] + atomicAdd(&fill[dst], 1);
    if (pos >= 0 && pos < EA) csrsrc[pos] = src;
}

// ------- xl(bf16-packed)/xr(fp32) = h @ Wl + bl, h @ Wr + br ----------------
#define GROWS 32
__global__ __launch_bounds__(128) void k_gemm2(
        const float* __restrict__ h,
        const float* __restrict__ Wl, const float* __restrict__ Wr,
        const float* __restrict__ bl, const float* __restrict__ br,
        unsigned* __restrict__ xlbf, float* __restrict__ xr) {
    __shared__ __align__(16) float hs[GROWS * HC];
    int tid = threadIdx.x;
    long row0 = (long)blockIdx.x * GROWS;
    for (int idx = tid; idx < GROWS * HC; idx += 128) {
        long g = row0 * HC + idx;
        hs[idx] = (g < (long)N_NODES * HC) ? h[g] : 0.f;
    }
    __syncthreads();
    int col = tid;
    float accL[GROWS], accR[GROWS];
#pragma unroll
    for (int r = 0; r < GROWS; r++) { accL[r] = 0.f; accR[r] = 0.f; }
    const float4* hs4 = (const float4*)hs;
    for (int k = 0; k < HC; k += 4) {
        float wl0 = Wl[(k + 0) * HC + col];
        float wl1 = Wl[(k + 1) * HC + col];
        float wl2 = Wl[(k + 2) * HC + col];
        float wl3 = Wl[(k + 3) * HC + col];
        float wr0 = Wr[(k + 0) * HC + col];
        float wr1 = Wr[(k + 1) * HC + col];
        float wr2 = Wr[(k + 2) * HC + col];
        float wr3 = Wr[(k + 3) * HC + col];
#pragma unroll
        for (int r = 0; r < GROWS; r++) {
            float4 hv = hs4[(r * HC + k) >> 2];
            accL[r] += hv.x * wl0 + hv.y * wl1 + hv.z * wl2 + hv.w * wl3;
            accR[r] += hv.x * wr0 + hv.y * wr1 + hv.z * wr2 + hv.w * wr3;
        }
    }
    float blv = bl[col], brv = br[col];
    int nrows = (int)((N_NODES - row0) < GROWS ? (N_NODES - row0) : GROWS);
    for (int r = 0; r < nrows; r++) {
        float vL = accL[r] + blv;
        float vP = __shfl_xor(vL, 1);          // partner column's value (lane pair)
        if ((col & 1) == 0)
            xlbf[(row0 + r) * (HC / 2) + (col >> 1)] =
                (unsigned)f2bfu(vL) | ((unsigned)f2bfu(vP) << 16);
        xr[(row0 + r) * HC + col] = accR[r] + brv;
    }
}

// --- GATv2 aggregation: 16 lanes/edge, 4 edges in flight/wave, flash merge ----
__global__ __launch_bounds__(256) void k_attn(
        const unsigned* __restrict__ xlbf, const float* __restrict__ xr,
        const int* __restrict__ off, const int* __restrict__ csrsrc,
        const float* __restrict__ att, const float* __restrict__ cb,
        float* __restrict__ hout) {
    int wave = threadIdx.x >> 6;
    int lane = threadIdx.x & 63;
    int node = blockIdx.x * 4 + wave;
    if (node >= N_NODES) return;
    int grp = lane >> 4;         // edge group 0..3
    int gl  = lane & 15;         // lane within group; handles features fb..fb+7
    int fb  = gl * 8;
    int head = fb >> 5;          // = gl/4, single head per lane

    // preload per-lane constants
    const float4* xrp = (const float4*)(xr + (long)node * HC + fb);
    float4 xa = xrp[0], xb = xrp[1];
    const float4* ap = (const float4*)(att + head * DIM + (fb & 31));
    float4 aa = ap[0], ab = ap[1];

    int e0 = off[node], e1 = off[node + 1];
    if (e0 < 0) e0 = 0;
    if (e1 > EA) e1 = EA;
    if (e1 <= e0) {
        if (grp == 0) {
            float4 z = make_float4(0.f, 0.f, 0.f, 0.f);
            ((float4*)(hout + (long)node * HC + fb))[0] = z;
            ((float4*)(hout + (long)node * HC + fb))[1] = z;
        }
        return;
    }
    int klast = e1 - 1;

    // software pipeline: 2 gathers in flight per group (8 per wave)
    int k0 = e0 + grp;
    int ka = k0 < klast ? k0 : klast;
    int kb = (k0 + 4) < klast ? (k0 + 4) : klast;
    int sa = csrsrc[ka];
    int sb = csrsrc[kb];
    uint4 u0 = ((const uint4*)(xlbf + (long)sa * (HC / 2)))[gl];
    uint4 u1 = ((const uint4*)(xlbf + (long)sb * (HC / 2)))[gl];

    float m = -1e30f, ssum = 0.f;
    float acc[8];
#pragma unroll
    for (int j = 0; j < 8; j++) acc[j] = 0.f;

    for (int kk = k0; kk < e1; kk += 4) {
        uint4 cur = u0;
        u0 = u1;
        int kp = (kk + 8) < klast ? (kk + 8) : klast;
        int sp = csrsrc[kp];
        u1 = ((const uint4*)(xlbf + (long)sp * (HC / 2)))[gl];

        // unpack 8 bf16 features
        float x0 = __uint_as_float(cur.x << 16);
        float x1 = __uint_as_float(cur.x & 0xffff0000u);
        float x2 = __uint_as_float(cur.y << 16);
        float x3 = __uint_as_float(cur.y & 0xffff0000u);
        float x4 = __uint_as_float(cur.z << 16);
        float x5 = __uint_as_float(cur.z & 0xffff0000u);
        float x6 = __uint_as_float(cur.w << 16);
        float x7 = __uint_as_float(cur.w & 0xffff0000u);
        // msg = xl + xr ; leaky = max(msg, SLOPE*msg)
        float m0 = x0 + xa.x, m1 = x1 + xa.y, m2 = x2 + xa.z, m3 = x3 + xa.w;
        float m4 = x4 + xb.x, m5 = x5 + xb.y, m6 = x6 + xb.z, m7 = x7 + xb.w;
        float l0 = fmaxf(m0, SLOPE * m0), l1 = fmaxf(m1, SLOPE * m1);
        float l2 = fmaxf(m2, SLOPE * m2), l3 = fmaxf(m3, SLOPE * m3);
        float l4 = fmaxf(m4, SLOPE * m4), l5 = fmaxf(m5, SLOPE * m5);
        float l6 = fmaxf(m6, SLOPE * m6), l7 = fmaxf(m7, SLOPE * m7);
        float p = l0 * aa.x + l1 * aa.y + l2 * aa.z + l3 * aa.w
                + l4 * ab.x + l5 * ab.y + l6 * ab.z + l7 * ab.w;
        // head dot = sum over the 4 lanes of this head's quad
        p += __shfl_xor(p, 1);
        p += __shfl_xor(p, 2);
        // online softmax update
        float mn = fmaxf(m, p);
        float sc = __expf(m - mn);
        float ex = __expf(p - mn);     // <= 1 always
        ssum = ssum * sc + ex;
        acc[0] = acc[0] * sc + ex * x0;
        acc[1] = acc[1] * sc + ex * x1;
        acc[2] = acc[2] * sc + ex * x2;
        acc[3] = acc[3] * sc + ex * x3;
        acc[4] = acc[4] * sc + ex * x4;
        acc[5] = acc[5] * sc + ex * x5;
        acc[6] = acc[6] * sc + ex * x6;
        acc[7] = acc[7] * sc + ex * x7;
        m = mn;
    }

    // flash-merge the 4 groups' partial states (xor 16, then 32)
#pragma unroll
    for (int d = 16; d <= 32; d <<= 1) {
        float mo = __shfl_xor(m, d);
        float so = __shfl_xor(ssum, d);
        float ao[8];
#pragma unroll
        for (int j = 0; j < 8; j++) ao[j] = __shfl_xor(acc[j], d);
        float mn = fmaxf(m, mo);
        float s1 = __expf(m - mn);
        float s2 = __expf(mo - mn);
        ssum = ssum * s1 + so * s2;
#pragma unroll
        for (int j = 0; j < 8; j++) acc[j] = acc[j] * s1 + ao[j] * s2;
        m = mn;
    }

    if (grp == 0) {
        float inv = 1.f / (ssum + 1e-16f);
        const float4* cbp = (const float4*)(cb + fb);
        float4 c0 = cbp[0], c1 = cbp[1];
        float4 o0, o1;
        o0.x = fmaxf(acc[0] * inv + c0.x, 0.f);
        o0.y = fmaxf(acc[1] * inv + c0.y, 0.f);
        o0.z = fmaxf(acc[2] * inv + c0.z, 0.f);
        o0.w = fmaxf(acc[3] * inv + c0.w, 0.f);
        o1.x = fmaxf(acc[4] * inv + c1.x, 0.f);
        o1.y = fmaxf(acc[5] * inv + c1.y, 0.f);
        o1.z = fmaxf(acc[6] * inv + c1.z, 0.f);
        o1.w = fmaxf(acc[7] * inv + c1.w, 0.f);
        float4* op = (float4*)(hout + (long)node * HC + fb);
        op[0] = o0;
        op[1] = o1;
    }
}

// ---------------- h2 = relu(h @ W1 + b1) : [N,128]@[128,32] ----------------
__global__ __launch_bounds__(256) void k_mlp1(
        const float* __restrict__ h, const float* __restrict__ W1,
        const float* __restrict__ b1, float* __restrict__ h2) {
    __shared__ float hs[8 * HC];
    __shared__ float w1s[HC * DIM];
    int tid = threadIdx.x;
    long row0 = (long)blockIdx.x * 8;
    for (int idx = tid; idx < HC * DIM; idx += 256) w1s[idx] = W1[idx];
    for (int idx = tid; idx < 8 * HC; idx += 256) {
        long g = row0 * HC + idx;
        hs[idx] = (g < (long)N_NODES * HC) ? h[g] : 0.f;
    }
    __syncthreads();
    int r = tid >> 5, c = tid & 31;
    float acc = b1[c];
    for (int k = 0; k < HC; k++) acc += hs[r * HC + k] * w1s[k * DIM + c];
    long row = row0 + r;
    if (row < N_NODES) h2[row * DIM + c] = acc > 0.f ? acc : 0.f;
}

// ---------------- h3 = relu(h2 @ W2 + b2) : [N,32]@[32,16] ----------------
__global__ __launch_bounds__(256) void k_mlp2(
        const float* __restrict__ h2, const float* __restrict__ W2,
        const float* __restrict__ b2, float* __restrict__ h3) {
    __shared__ float hs[16 * DIM];
    __shared__ float w2s[DIM * DIM2];
    int tid = threadIdx.x;
    long row0 = (long)blockIdx.x * 16;
    for (int idx = tid; idx < DIM * DIM2; idx += 256) w2s[idx] = W2[idx];
    for (int idx = tid; idx < 16 * DIM; idx += 256) {
        long g = row0 * DIM + idx;
        hs[idx] = (g < (long)N_NODES * DIM) ? h2[g] : 0.f;
    }
    __syncthreads();
    int r = tid >> 4, c = tid & 15;
    float acc = b2[c];
    for (int k = 0; k < DIM; k++) acc += hs[r * DIM + k] * w2s[k * DIM2 + c];
    long row = row0 + r;
    if (row < N_NODES) h3[row * DIM2 + c] = acc > 0.f ? acc : 0.f;
}

// ------- fused head: out0 = concat(h3[src],h3[dst]) @ W3 + b3, eout = concat ----
__global__ __launch_bounds__(256) void k_out(
        const float* __restrict__ h3, const int* __restrict__ eidx,
        const float* __restrict__ W3, const float* __restrict__ b3,
        void* __restrict__ dout, const int* __restrict__ flags) {
    __shared__ float w3s[2 * DIM2 * NCLS];
    __shared__ float bs[NCLS];
    int tid = threadIdx.x;
    if (tid < 2 * DIM2 * NCLS) w3s[tid] = W3[tid];
    if (tid < NCLS) bs[tid] = b3[tid];
    __syncthreads();
    int e = blockIdx.x * 256 + tid;
    if (e >= E_EDGES) return;
    int src = eidx[e], dst = eidx[E_EDGES + e];
    float v[2 * DIM2];
    const float4* ps = (const float4*)(h3 + (long)src * DIM2);
    const float4* pd = (const float4*)(h3 + (long)dst * DIM2);
#pragma unroll
    for (int q = 0; q < 4; q++) {
        float4 t = ps[q];
        v[q * 4 + 0] = t.x; v[q * 4 + 1] = t.y; v[q * 4 + 2] = t.z; v[q * 4 + 3] = t.w;
    }
#pragma unroll
    for (int q = 0; q < 4; q++) {
        float4 t = pd[q];
        v[16 + q * 4 + 0] = t.x; v[16 + q * 4 + 1] = t.y; v[16 + q * 4 + 2] = t.z; v[16 + q * 4 + 3] = t.w;
    }
    float o[NCLS];
#pragma unroll
    for (int j = 0; j < NCLS; j++) {
        float acc = bs[j];
#pragma unroll
        for (int k = 0; k < 2 * DIM2; k++) acc += v[k] * w3s[k * NCLS + j];
        o[j] = acc;
    }
    if (flags[0]) {
        float* out0 = (float*)dout;
#pragma unroll
        for (int j = 0; j < NCLS; j++) out0[(long)e * NCLS + j] = o[j];
        float4* eo = (float4*)((float*)dout + (long)E_EDGES * NCLS) + (long)e * 8;
#pragma unroll
        for (int q = 0; q < 8; q++)
            eo[q] = make_float4(v[q * 4], v[q * 4 + 1], v[q * 4 + 2], v[q * 4 + 3]);
    } else {
        bf16* out0 = (bf16*)dout;
#pragma unroll
        for (int j = 0; j < NCLS; j++) out0[(long)e * NCLS + j] = __float2bfloat16(o[j]);
        uint4* eo = (uint4*)((bf16*)dout + (long)E_EDGES * NCLS) + (long)e * 4;
#pragma unroll
        for (int q = 0; q < 4; q++) {
            uint4 w;
            w.x = (unsigned)f2bfu(v[q * 8 + 0]) | ((unsigned)f2bfu(v[q * 8 + 1]) << 16);
            w.y = (unsigned)f2bfu(v[q * 8 + 2]) | ((unsigned)f2bfu(v[q * 8 + 3]) << 16);
            w.z = (unsigned)f2bfu(v[q * 8 + 4]) | ((unsigned)f2bfu(v[q * 8 + 5]) << 16);
            w.w = (unsigned)f2bfu(v[q * 8 + 6]) | ((unsigned)f2bfu(v[q * 8 + 7]) << 16);
            eo[q] = w;
        }
    }
}

extern "C" void kernel_launch(void* const* d_in, const int* in_sizes, int n_in,
                              void* d_out, int out_size, void* d_ws, size_t ws_size,
                              hipStream_t stream) {
    // ---- workspace layout (4-byte word offsets) ----
    float* wsf   = (float*)d_ws;
    int*   flags = (int*)d_ws;                     // 16 words
    float* h     = wsf + 16;                       // 6,400,000
    float* xl    = h  + (long)N_NODES * HC;        // 6,400,000 words reserved (xlbf uses half)
    float* xr    = xl + (long)N_NODES * HC;        // 6,400,000
    float* prm   = xr + (long)N_NODES * HC;        // 110,000
    int*   eidx  = (int*)(prm + 110000);           // 1,600,000
    int*   off   = eidx + 2 * E_EDGES;             // 50,001
    int*   fill  = off + (N_NODES + 1);            // 50,000
    int*   csr   = fill + N_NODES;                 // 850,000
    int*   part  = csr + EA;                       // 64
    unsigned* xlbf = (unsigned*)xl;                // N*64 packed bf16x2
    // h2/h3 overlay the xl slot (free after conv layers)
    float* h2 = xl;
    float* h3 = xl + (long)N_NODES * DIM;

    // param block offsets (floats) — must match k_cvt_all's segment table
    float* pWl = prm + 0;        // 3*16384
    float* pWr = prm + 49152;    // 3*16384
    float* pbl = prm + 98304;    // 3*128
    float* pbr = prm + 98688;
    float* patt= prm + 99072;
    float* pcb = prm + 99456;
    float* pW1 = prm + 99840;    // 4096
    float* pb1 = prm + 103936;   // 32
    float* pW2 = prm + 103968;   // 512
    float* pb2 = prm + 104480;   // 16
    float* pW3 = prm + 104496;   // 192
    float* pb3 = prm + 104688;   // 6

    // 1. detect dtypes (deterministic function of pristine inputs)
    k_detect<<<1, 256, 0, stream>>>(d_in[3], d_in[1], flags);

    // 2. normalize all float inputs in one launch; indices separately
    k_cvt_all<<<(XN + 104694 + 255) / 256, 256, 0, stream>>>(
        d_in[0], d_in[3], d_in[4], d_in[5], d_in[6], d_in[7], d_in[8],
        d_in[9], d_in[10], d_in[11], d_in[12], d_in[13], d_in[14],
        h, prm, flags);
    k_cvti<<<(2 * E_EDGES + 255) / 256, 256, 0, stream>>>(d_in[1], eidx, 2 * E_EDGES, flags);

    // 3. CSR build (dst-sorted incoming edge lists, self-loops appended)
    k_zero<<<(2 * N_NODES + 1 + 255) / 256, 256, 0, stream>>>(off, fill);
    k_hist<<<(EA + 255) / 256, 256, 0, stream>>>(eidx, off);
    k_scan1<<<NCHUNK, 1024, 0, stream>>>(off, part);
    k_scan2<<<1, 64, 0, stream>>>(part);
    k_scan3<<<NCHUNK, 1024, 0, stream>>>(off, part);
    k_scatter<<<(EA + 255) / 256, 256, 0, stream>>>(eidx, off, fill, csr);

    // 4. three GATv2 layers (h updated in place by k_attn)
    for (int i = 0; i < 3; i++) {
        k_gemm2<<<(N_NODES + GROWS - 1) / GROWS, 128, 0, stream>>>(
            h, pWl + (long)i * HC * HC, pWr + (long)i * HC * HC,
            pbl + (long)i * HC, pbr + (long)i * HC, xlbf, xr);
        k_attn<<<(N_NODES + 3) / 4, 256, 0, stream>>>(
            xlbf, xr, off, csr, patt + (long)i * HEADS * DIM, pcb + (long)i * HC, h);
    }

    // 5. MLP head
    k_mlp1<<<(N_NODES + 7) / 8, 256, 0, stream>>>(h, pW1, pb1, h2);
    k_mlp2<<<(N_NODES + 15) / 16, 256, 0, stream>>>(h2, pW2, pb2, h3);

    // 6. fused outputs (single gather of h3 rows)
    k_out<<<(E_EDGES + 255) / 256, 256, 0, stream>>>(h3, eidx, pW3, pb3, d_out, flags);
}

// Round 6
// 561.930 us; speedup vs baseline: 2.5289x; 1.3541x over previous
//
#include <hip/hip_runtime.h>
#include <hip/hip_bf16.h>

typedef __hip_bfloat16 bf16;
typedef __attribute__((ext_vector_type(8))) short bf16x8;
typedef __attribute__((ext_vector_type(4))) float f32x4;

#define N_NODES 50000
#define E_EDGES 800000
#define EA (E_EDGES + N_NODES)   // 850000 edges incl self-loops
#define HC 128                   // heads*dim
#define HEADS 4
#define DIM 32
#define DIM2 16
#define NCLS 6
#define SLOPE 0.2f
#define NCHUNK ((N_NODES + 1023) / 1024)   // 49
#define XN (N_NODES * HC)                  // 6,400,000
#define GM 32                              // nodes per GEMM block
#define HSTRIDE 152                        // padded ushort stride (304B: 16B-aligned, 2-way banks)
#define WSWZ_L 32768                       // swizzled weight ushorts per layer (256*128)

__device__ __forceinline__ float b2f(bf16 v) { return __bfloat162float(v); }
__device__ __forceinline__ unsigned short f2bfu(float f) {
    bf16 b = __float2bfloat16(f);
    return *(unsigned short*)&b;
}

// ---------------- dtype detector ----------------
// flags[0]=1 -> float inputs (and output) are fp32; 0 -> bf16
// flags[1]=1 -> edge_index is int64; 0 -> int32
__global__ __launch_bounds__(256) void k_detect(const void* wptr, const void* eptr,
                                                int* __restrict__ flags) {
    __shared__ int sb[256], sn[256];
    int tid = threadIdx.x;
    const unsigned short* w = (const unsigned short*)wptr;
    int badf = 0;
    for (int i = tid; i < 4096; i += 256) {
        unsigned v = w[i];
        unsigned ex = (v >> 7) & 0xFF;
        if (v != 0 && (ex < 90 || ex > 150)) badf++;
    }
    const int* ei = (const int*)eptr;
    int nz = 0;
    for (int i = tid; i < 2048; i += 256) {
        if (ei[2 * i + 1] != 0) nz++;
    }
    sb[tid] = badf; sn[tid] = nz;
    __syncthreads();
    for (int ofs = 128; ofs > 0; ofs >>= 1) {
        if (tid < ofs) { sb[tid] += sb[tid + ofs]; sn[tid] += sn[tid + ofs]; }
        __syncthreads();
    }
    if (tid == 0) {
        flags[0] = (sb[0] > 64) ? 1 : 0;
        flags[1] = (sn[0] < 64) ? 1 : 0;
    }
}

// ---------- single fused conversion of x + all params to fp32 scratch ----------
__global__ void k_cvt_all(const void* sx, const void* sWl, const void* sWr,
                          const void* sbl, const void* sbr, const void* satt,
                          const void* scb, const void* sW1, const void* sb1,
                          const void* sW2, const void* sb2, const void* sW3,
                          const void* sb3,
                          float* __restrict__ h, float* __restrict__ prm,
                          const int* __restrict__ flags) {
    int i = blockIdx.x * blockDim.x + threadIdx.x;
    if (i >= XN + 104694) return;
    const void* src; float* dst; int off;
    if (i < XN) { src = sx; dst = h; off = i; }
    else {
        int j = i - XN;
        if      (j < 49152)  { src = sWl;  dst = prm;           off = j; }
        else if (j < 98304)  { src = sWr;  dst = prm + 49152;   off = j - 49152; }
        else if (j < 98688)  { src = sbl;  dst = prm + 98304;   off = j - 98304; }
        else if (j < 99072)  { src = sbr;  dst = prm + 98688;   off = j - 98688; }
        else if (j < 99456)  { src = satt; dst = prm + 99072;   off = j - 99072; }
        else if (j < 99840)  { src = scb;  dst = prm + 99456;   off = j - 99456; }
        else if (j < 103936) { src = sW1;  dst = prm + 99840;   off = j - 99840; }
        else if (j < 103968) { src = sb1;  dst = prm + 103936;  off = j - 103936; }
        else if (j < 104480) { src = sW2;  dst = prm + 103968;  off = j - 103968; }
        else if (j < 104496) { src = sb2;  dst = prm + 104480;  off = j - 104480; }
        else if (j < 104688) { src = sW3;  dst = prm + 104496;  off = j - 104496; }
        else                 { src = sb3;  dst = prm + 104688;  off = j - 104688; }
    }
    float v = flags[0] ? ((const float*)src)[off] : b2f(((const bf16*)src)[off]);
    dst[off] = v;
}

__global__ void k_cvti(const void* __restrict__ src, int* __restrict__ dst, int n,
                       const int* __restrict__ flags) {
    int i = blockIdx.x * blockDim.x + threadIdx.x;
    if (i >= n) return;
    int v;
    if (flags[1]) v = (int)((const long long*)src)[i];
    else          v = ((const int*)src)[i];
    if (v < 0) v = 0;
    if (v >= N_NODES) v = N_NODES - 1;
    dst[i] = v;
}

// ------- swizzle Wl/Wr (fp32) into MFMA B-fragment order, bf16 ----------------
// wswz[L][ntile][ks][lane][j]: col = ntile*16+(lane&15), k = ks*32+(lane>>4)*8+j
__global__ void k_wswz(const float* __restrict__ prm, unsigned short* __restrict__ wswz) {
    int i = blockIdx.x * blockDim.x + threadIdx.x;
    if (i >= 3 * WSWZ_L) return;
    int L = i / WSWZ_L;
    int e = i % WSWZ_L;
    int ntile = e >> 11;            // /2048
    int r2 = e & 2047;
    int ks = r2 >> 9;               // /512
    int r3 = r2 & 511;
    int lane = r3 >> 3;
    int j = r3 & 7;
    int col = ntile * 16 + (lane & 15);
    int k = ks * 32 + (lane >> 4) * 8 + j;
    float v;
    if (col < HC) v = prm[L * HC * HC + k * HC + col];                    // Wl
    else          v = prm[49152 + L * HC * HC + k * HC + (col - HC)];     // Wr
    wswz[i] = f2bfu(v);
}

// ---------------- CSR build ----------------
__global__ void k_zero(int* __restrict__ off, int* __restrict__ fill) {
    int i = blockIdx.x * blockDim.x + threadIdx.x;
    if (i <= N_NODES) off[i] = 0;
    if (i < N_NODES) fill[i] = 0;
}

__global__ void k_hist(const int* __restrict__ eidx, int* __restrict__ off) {
    int e = blockIdx.x * blockDim.x + threadIdx.x;
    if (e >= EA) return;
    int dst = (e < E_EDGES) ? eidx[E_EDGES + e] : (e - E_EDGES);
    atomicAdd(&off[dst], 1);
}

__global__ __launch_bounds__(1024) void k_scan1(int* __restrict__ off, int* __restrict__ part) {
    __shared__ int s[1024];
    int tid = threadIdx.x;
    int i = blockIdx.x * 1024 + tid;
    int v = (i < N_NODES) ? off[i] : 0;
    s[tid] = v;
    __syncthreads();
    for (int o = 1; o < 1024; o <<= 1) {
        int t = (tid >= o) ? s[tid - o] : 0;
        __syncthreads();
        s[tid] += t;
        __syncthreads();
    }
    if (i < N_NODES) off[i] = s[tid] - v;
    if (tid == 1023) part[blockIdx.x] = s[1023];
}

__global__ __launch_bounds__(64) void k_scan2(int* __restrict__ part) {
    int tid = threadIdx.x;
    int v = (tid < NCHUNK) ? part[tid] : 0;
    int orig = v;
    for (int o = 1; o < 64; o <<= 1) {
        int t = __shfl_up(v, o);
        if (tid >= o) v += t;
    }
    if (tid < NCHUNK) part[tid] = v - orig;
}

__global__ __launch_bounds__(1024) void k_scan3(int* __restrict__ off, const int* __restrict__ part) {
    int i = blockIdx.x * 1024 + threadIdx.x;
    if (i < N_NODES) off[i] += part[blockIdx.x];
    if (i == 0) off[N_NODES] = EA;
}

__global__ void k_scatter(const int* __restrict__ eidx, const int* __restrict__ off,
                          int* __restrict__ fill, int* __restrict__ csrsrc) {
    int e = blockIdx.x * blockDim.x + threadIdx.x;
    if (e >= EA) return;
    int src, dst;
    if (e < E_EDGES) { src = eidx[e]; dst = eidx[E_EDGES + e]; }
    else             { src = dst = e - E_EDGES; }
    int pos = off[dst] + atomicAdd(&fill[dst], 1);
    if (pos >= 0 && pos < EA) csrsrc[pos] = src;
}

// ------- MFMA GEMM: xl(bf16-packed) cols 0..127, xr(fp32) cols 128..255 --------
// block = 256 thr / 4 waves, 32 nodes; wave w owns 64 combined cols.
__global__ __launch_bounds__(256) void k_gemm_mfma(
        const float* __restrict__ h,
        const unsigned short* __restrict__ wswz,
        const float* __restrict__ bl, const float* __restrict__ br,
        unsigned* __restrict__ xlbf, float* __restrict__ xr) {
    __shared__ unsigned short hs[GM * HSTRIDE];   // 9728 B
    int tid = threadIdx.x;
    int wave = tid >> 6, lane = tid & 63;
    long row0 = (long)blockIdx.x * GM;

    // stage h tile as bf16 pairs into padded LDS
    for (int idx = tid; idx < GM * 64; idx += 256) {
        int r = idx >> 6, cp = idx & 63;
        float v0 = 0.f, v1 = 0.f;
        if (row0 + r < N_NODES) {
            const float2 hv = ((const float2*)(h + (row0 + r) * HC))[cp];
            v0 = hv.x; v1 = hv.y;
        }
        unsigned* dst = (unsigned*)&hs[r * HSTRIDE + cp * 2];
        *dst = (unsigned)f2bfu(v0) | ((unsigned)f2bfu(v1) << 16);
    }
    __syncthreads();

    int q = lane >> 4, l16 = lane & 15;
    for (int nt = 0; nt < 4; nt++) {
        int colbase = wave * 64 + nt * 16;
        int col = colbase + l16;          // 0..255 combined
        int ntile = colbase >> 4;
        f32x4 acc0 = {0.f, 0.f, 0.f, 0.f};
        f32x4 acc1 = {0.f, 0.f, 0.f, 0.f};
#pragma unroll
        for (int ks = 0; ks < 4; ks++) {
            bf16x8 bfrag = *(const bf16x8*)(wswz + (((ntile * 4 + ks) * 64 + lane) << 3));
            bf16x8 a0 = *(const bf16x8*)(hs + l16 * HSTRIDE + ks * 32 + q * 8);
            bf16x8 a1 = *(const bf16x8*)(hs + (16 + l16) * HSTRIDE + ks * 32 + q * 8);
            acc0 = __builtin_amdgcn_mfma_f32_16x16x32_bf16(a0, bfrag, acc0, 0, 0, 0);
            acc1 = __builtin_amdgcn_mfma_f32_16x16x32_bf16(a1, bfrag, acc1, 0, 0, 0);
        }
        // D: row = q*4+reg (within 16-node tile), col = l16
        if (col < HC) {
            float bias = bl[col];
#pragma unroll
            for (int reg = 0; reg < 4; reg++) {
                float v0 = acc0[reg] + bias;
                float v1 = acc1[reg] + bias;
                float p0 = __shfl_xor(v0, 1);
                float p1 = __shfl_xor(v1, 1);
                if ((lane & 1) == 0) {
                    long n0 = row0 + q * 4 + reg;
                    long n1 = row0 + 16 + q * 4 + reg;
                    unsigned u0 = (unsigned)f2bfu(v0) | ((unsigned)f2bfu(p0) << 16);
                    unsigned u1 = (unsigned)f2bfu(v1) | ((unsigned)f2bfu(p1) << 16);
                    int cp = col >> 1;
                    if (n0 < N_NODES) xlbf[n0 * (HC / 2) + cp] = u0;
                    if (n1 < N_NODES) xlbf[n1 * (HC / 2) + cp] = u1;
                }
            }
        } else {
            int c = col - HC;
            float bias = br[c];
#pragma unroll
            for (int reg = 0; reg < 4; reg++) {
                long n0 = row0 + q * 4 + reg;
                long n1 = row0 + 16 + q * 4 + reg;
                if (n0 < N_NODES) xr[n0 * HC + c] = acc0[reg] + bias;
                if (n1 < N_NODES) xr[n1 * HC + c] = acc1[reg] + bias;
            }
        }
    }
}

// --- GATv2 aggregation: 16 lanes/edge, 4 edges in flight/wave, flash merge ----
__global__ __launch_bounds__(256) void k_attn(
        const unsigned* __restrict__ xlbf, const float* __restrict__ xr,
        const int* __restrict__ off, const int* __restrict__ csrsrc,
        const float* __restrict__ att, const float* __restrict__ cb,
        float* __restrict__ hout) {
    int wave = threadIdx.x >> 6;
    int lane = threadIdx.x & 63;
    int node = blockIdx.x * 4 + wave;
    if (node >= N_NODES) return;
    int grp = lane >> 4;
    int gl  = lane & 15;
    int fb  = gl * 8;
    int head = fb >> 5;

    const float4* xrp = (const float4*)(xr + (long)node * HC + fb);
    float4 xa = xrp[0], xb = xrp[1];
    const float4* ap = (const float4*)(att + head * DIM + (fb & 31));
    float4 aa = ap[0], ab = ap[1];

    int e0 = off[node], e1 = off[node + 1];
    if (e0 < 0) e0 = 0;
    if (e1 > EA) e1 = EA;
    if (e1 <= e0) {
        if (grp == 0) {
            float4 z = make_float4(0.f, 0.f, 0.f, 0.f);
            ((float4*)(hout + (long)node * HC + fb))[0] = z;
            ((float4*)(hout + (long)node * HC + fb))[1] = z;
        }
        return;
    }
    int klast = e1 - 1;

    int k0 = e0 + grp;
    int ka = k0 < klast ? k0 : klast;
    int kb = (k0 + 4) < klast ? (k0 + 4) : klast;
    int sa = csrsrc[ka];
    int sb = csrsrc[kb];
    uint4 u0 = ((const uint4*)(xlbf + (long)sa * (HC / 2)))[gl];
    uint4 u1 = ((const uint4*)(xlbf + (long)sb * (HC / 2)))[gl];

    float m = -1e30f, ssum = 0.f;
    float acc[8];
#pragma unroll
    for (int j = 0; j < 8; j++) acc[j] = 0.f;

    for (int kk = k0; kk < e1; kk += 4) {
        uint4 cur = u0;
        u0 = u1;
        int kp = (kk + 8) < klast ? (kk + 8) : klast;
        int sp = csrsrc[kp];
        u1 = ((const uint4*)(xlbf + (long)sp * (HC / 2)))[gl];

        float x0 = __uint_as_float(cur.x << 16);
        float x1 = __uint_as_float(cur.x & 0xffff0000u);
        float x2 = __uint_as_float(cur.y << 16);
        float x3 = __uint_as_float(cur.y & 0xffff0000u);
        float x4 = __uint_as_float(cur.z << 16);
        float x5 = __uint_as_float(cur.z & 0xffff0000u);
        float x6 = __uint_as_float(cur.w << 16);
        float x7 = __uint_as_float(cur.w & 0xffff0000u);
        float m0 = x0 + xa.x, m1 = x1 + xa.y, m2 = x2 + xa.z, m3 = x3 + xa.w;
        float m4 = x4 + xb.x, m5 = x5 + xb.y, m6 = x6 + xb.z, m7 = x7 + xb.w;
        float l0 = fmaxf(m0, SLOPE * m0), l1 = fmaxf(m1, SLOPE * m1);
        float l2 = fmaxf(m2, SLOPE * m2), l3 = fmaxf(m3, SLOPE * m3);
        float l4 = fmaxf(m4, SLOPE * m4), l5 = fmaxf(m5, SLOPE * m5);
        float l6 = fmaxf(m6, SLOPE * m6), l7 = fmaxf(m7, SLOPE * m7);
        float p = l0 * aa.x + l1 * aa.y + l2 * aa.z + l3 * aa.w
                + l4 * ab.x + l5 * ab.y + l6 * ab.z + l7 * ab.w;
        p += __shfl_xor(p, 1);
        p += __shfl_xor(p, 2);
        float mn = fmaxf(m, p);
        float sc = __expf(m - mn);
        float ex = __expf(p - mn);
        ssum = ssum * sc + ex;
        acc[0] = acc[0] * sc + ex * x0;
        acc[1] = acc[1] * sc + ex * x1;
        acc[2] = acc[2] * sc + ex * x2;
        acc[3] = acc[3] * sc + ex * x3;
        acc[4] = acc[4] * sc + ex * x4;
        acc[5] = acc[5] * sc + ex * x5;
        acc[6] = acc[6] * sc + ex * x6;
        acc[7] = acc[7] * sc + ex * x7;
        m = mn;
    }

#pragma unroll
    for (int d = 16; d <= 32; d <<= 1) {
        float mo = __shfl_xor(m, d);
        float so = __shfl_xor(ssum, d);
        float ao[8];
#pragma unroll
        for (int j = 0; j < 8; j++) ao[j] = __shfl_xor(acc[j], d);
        float mn = fmaxf(m, mo);
        float s1 = __expf(m - mn);
        float s2 = __expf(mo - mn);
        ssum = ssum * s1 + so * s2;
#pragma unroll
        for (int j = 0; j < 8; j++) acc[j] = acc[j] * s1 + ao[j] * s2;
        m = mn;
    }

    if (grp == 0) {
        float inv = 1.f / (ssum + 1e-16f);
        const float4* cbp = (const float4*)(cb + fb);
        float4 c0 = cbp[0], c1 = cbp[1];
        float4 o0, o1;
        o0.x = fmaxf(acc[0] * inv + c0.x, 0.f);
        o0.y = fmaxf(acc[1] * inv + c0.y, 0.f);
        o0.z = fmaxf(acc[2] * inv + c0.z, 0.f);
        o0.w = fmaxf(acc[3] * inv + c0.w, 0.f);
        o1.x = fmaxf(acc[4] * inv + c1.x, 0.f);
        o1.y = fmaxf(acc[5] * inv + c1.y, 0.f);
        o1.z = fmaxf(acc[6] * inv + c1.z, 0.f);
        o1.w = fmaxf(acc[7] * inv + c1.w, 0.f);
        float4* op = (float4*)(hout + (long)node * HC + fb);
        op[0] = o0;
        op[1] = o1;
    }
}

// ---------------- h2 = relu(h @ W1 + b1) : [N,128]@[128,32] ----------------
__global__ __launch_bounds__(256) void k_mlp1(
        const float* __restrict__ h, const float* __restrict__ W1,
        const float* __restrict__ b1, float* __restrict__ h2) {
    __shared__ float hs[8 * HC];
    __shared__ float w1s[HC * DIM];
    int tid = threadIdx.x;
    long row0 = (long)blockIdx.x * 8;
    for (int idx = tid; idx < HC * DIM; idx += 256) w1s[idx] = W1[idx];
    for (int idx = tid; idx < 8 * HC; idx += 256) {
        long g = row0 * HC + idx;
        hs[idx] = (g < (long)N_NODES * HC) ? h[g] : 0.f;
    }
    __syncthreads();
    int r = tid >> 5, c = tid & 31;
    float acc = b1[c];
    for (int k = 0; k < HC; k++) acc += hs[r * HC + k] * w1s[k * DIM + c];
    long row = row0 + r;
    if (row < N_NODES) h2[row * DIM + c] = acc > 0.f ? acc : 0.f;
}

// ---------------- h3 = relu(h2 @ W2 + b2) : [N,32]@[32,16] ----------------
__global__ __launch_bounds__(256) void k_mlp2(
        const float* __restrict__ h2, const float* __restrict__ W2,
        const float* __restrict__ b2, float* __restrict__ h3) {
    __shared__ float hs[16 * DIM];
    __shared__ float w2s[DIM * DIM2];
    int tid = threadIdx.x;
    long row0 = (long)blockIdx.x * 16;
    for (int idx = tid; idx < DIM * DIM2; idx += 256) w2s[idx] = W2[idx];
    for (int idx = tid; idx < 16 * DIM; idx += 256) {
        long g = row0 * DIM + idx;
        hs[idx] = (g < (long)N_NODES * DIM) ? h2[g] : 0.f;
    }
    __syncthreads();
    int r = tid >> 4, c = tid & 15;
    float acc = b2[c];
    for (int k = 0; k < DIM; k++) acc += hs[r * DIM + k] * w2s[k * DIM2 + c];
    long row = row0 + r;
    if (row < N_NODES) h3[row * DIM2 + c] = acc > 0.f ? acc : 0.f;
}

// ------- fused head: out0 = concat(h3[src],h3[dst]) @ W3 + b3, eout = concat ----
__global__ __launch_bounds__(256) void k_out(
        const float* __restrict__ h3, const int* __restrict__ eidx,
        const float* __restrict__ W3, const float* __restrict__ b3,
        void* __restrict__ dout, const int* __restrict__ flags) {
    __shared__ float w3s[2 * DIM2 * NCLS];
    __shared__ float bs[NCLS];
    int tid = threadIdx.x;
    if (tid < 2 * DIM2 * NCLS) w3s[tid] = W3[tid];
    if (tid < NCLS) bs[tid] = b3[tid];
    __syncthreads();
    int e = blockIdx.x * 256 + tid;
    if (e >= E_EDGES) return;
    int src = eidx[e], dst = eidx[E_EDGES + e];
    float v[2 * DIM2];
    const float4* ps = (const float4*)(h3 + (long)src * DIM2);
    const float4* pd = (const float4*)(h3 + (long)dst * DIM2);
#pragma unroll
    for (int q = 0; q < 4; q++) {
        float4 t = ps[q];
        v[q * 4 + 0] = t.x; v[q * 4 + 1] = t.y; v[q * 4 + 2] = t.z; v[q * 4 + 3] = t.w;
    }
#pragma unroll
    for (int q = 0; q < 4; q++) {
        float4 t = pd[q];
        v[16 + q * 4 + 0] = t.x; v[16 + q * 4 + 1] = t.y; v[16 + q * 4 + 2] = t.z; v[16 + q * 4 + 3] = t.w;
    }
    float o[NCLS];
#pragma unroll
    for (int j = 0; j < NCLS; j++) {
        float acc = bs[j];
#pragma unroll
        for (int k = 0; k < 2 * DIM2; k++) acc += v[k] * w3s[k * NCLS + j];
        o[j] = acc;
    }
    if (flags[0]) {
        float* out0 = (float*)dout;
#pragma unroll
        for (int j = 0; j < NCLS; j++) out0[(long)e * NCLS + j] = o[j];
        float4* eo = (float4*)((float*)dout + (long)E_EDGES * NCLS) + (long)e * 8;
#pragma unroll
        for (int q = 0; q < 8; q++)
            eo[q] = make_float4(v[q * 4], v[q * 4 + 1], v[q * 4 + 2], v[q * 4 + 3]);
    } else {
        bf16* out0 = (bf16*)dout;
#pragma unroll
        for (int j = 0; j < NCLS; j++) out0[(long)e * NCLS + j] = __float2bfloat16(o[j]);
        uint4* eo = (uint4*)((bf16*)dout + (long)E_EDGES * NCLS) + (long)e * 4;
#pragma unroll
        for (int q = 0; q < 4; q++) {
            uint4 w;
            w.x = (unsigned)f2bfu(v[q * 8 + 0]) | ((unsigned)f2bfu(v[q * 8 + 1]) << 16);
            w.y = (unsigned)f2bfu(v[q * 8 + 2]) | ((unsigned)f2bfu(v[q * 8 + 3]) << 16);
            w.z = (unsigned)f2bfu(v[q * 8 + 4]) | ((unsigned)f2bfu(v[q * 8 + 5]) << 16);
            w.w = (unsigned)f2bfu(v[q * 8 + 6]) | ((unsigned)f2bfu(v[q * 8 + 7]) << 16);
            eo[q] = w;
        }
    }
}

extern "C" void kernel_launch(void* const* d_in, const int* in_sizes, int n_in,
                              void* d_out, int out_size, void* d_ws, size_t ws_size,
                              hipStream_t stream) {
    // ---- workspace layout (4-byte word offsets) ----
    float* wsf   = (float*)d_ws;
    int*   flags = (int*)d_ws;                     // 16 words
    float* h     = wsf + 16;                       // 6,400,000
    float* xl    = h  + (long)N_NODES * HC;        // 6,400,000 words reserved (xlbf uses half)
    float* xr    = xl + (long)N_NODES * HC;        // 6,400,000
    float* prm   = xr + (long)N_NODES * HC;        // 110,000
    int*   eidx  = (int*)(prm + 110000);           // 1,600,000
    int*   off   = eidx + 2 * E_EDGES;             // 50,001
    int*   fill  = off + (N_NODES + 1);            // 50,000
    int*   csr   = fill + N_NODES;                 // 850,000
    int*   part  = csr + EA;                       // 64
    unsigned short* wswz = (unsigned short*)(part + 64);  // 3*32768 ushorts
    unsigned* xlbf = (unsigned*)xl;                // N*64 packed bf16x2
    float* h2 = xl;                                // overlay (free after convs)
    float* h3 = xl + (long)N_NODES * DIM;

    // param block offsets (floats) — must match k_cvt_all's segment table
    float* pWl = prm + 0;        // 3*16384
    float* pbl = prm + 98304;
    float* pbr = prm + 98688;
    float* patt= prm + 99072;
    float* pcb = prm + 99456;
    float* pW1 = prm + 99840;
    float* pb1 = prm + 103936;
    float* pW2 = prm + 103968;
    float* pb2 = prm + 104480;
    float* pW3 = prm + 104496;
    float* pb3 = prm + 104688;

    // 1. detect dtypes (deterministic function of pristine inputs)
    k_detect<<<1, 256, 0, stream>>>(d_in[3], d_in[1], flags);

    // 2. normalize inputs; swizzle weights for MFMA
    k_cvt_all<<<(XN + 104694 + 255) / 256, 256, 0, stream>>>(
        d_in[0], d_in[3], d_in[4], d_in[5], d_in[6], d_in[7], d_in[8],
        d_in[9], d_in[10], d_in[11], d_in[12], d_in[13], d_in[14],
        h, prm, flags);
    k_cvti<<<(2 * E_EDGES + 255) / 256, 256, 0, stream>>>(d_in[1], eidx, 2 * E_EDGES, flags);
    k_wswz<<<(3 * WSWZ_L + 255) / 256, 256, 0, stream>>>(pWl, wswz);

    // 3. CSR build
    k_zero<<<(2 * N_NODES + 1 + 255) / 256, 256, 0, stream>>>(off, fill);
    k_hist<<<(EA + 255) / 256, 256, 0, stream>>>(eidx, off);
    k_scan1<<<NCHUNK, 1024, 0, stream>>>(off, part);
    k_scan2<<<1, 64, 0, stream>>>(part);
    k_scan3<<<NCHUNK, 1024, 0, stream>>>(off, part);
    k_scatter<<<(EA + 255) / 256, 256, 0, stream>>>(eidx, off, fill, csr);

    // 4. three GATv2 layers (h updated in place by k_attn)
    for (int i = 0; i < 3; i++) {
        k_gemm_mfma<<<(N_NODES + GM - 1) / GM, 256, 0, stream>>>(
            h, wswz + (long)i * WSWZ_L, pbl + (long)i * HC, pbr + (long)i * HC,
            xlbf, xr);
        k_attn<<<(N_NODES + 3) / 4, 256, 0, stream>>>(
            xlbf, xr, off, csr, patt + (long)i * HEADS * DIM, pcb + (long)i * HC, h);
    }

    // 5. MLP head
    k_mlp1<<<(N_NODES + 7) / 8, 256, 0, stream>>>(h, pW1, pb1, h2);
    k_mlp2<<<(N_NODES + 15) / 16, 256, 0, stream>>>(h2, pW2, pb2, h3);

    // 6. fused outputs (single gather of h3 rows)
    k_out<<<(E_EDGES + 255) / 256, 256, 0, stream>>>(h3, eidx, pW3, pb3, d_out, flags);
}